// Round 1
// baseline (676.968 us; speedup 1.0000x reference)
//
#include <hip/hip_runtime.h>
#include <cstdio>
#include <cstdint>

// ---------------- problem constants ----------------
static const int kNV = 200000;
static const int kNT = 800000;
static const int kNUV = 895;                       // ceil(sqrt((2*NT+1)//2))
#define UVS_ROWS   3204100LL                       // kNUV*kNUV*4
#define UVS_FLOATS 6408200LL                       // UVS_ROWS*2
#define CAP 3300000                                // max crossing-edge instances (<= 4*NT = 3.2M)

__device__ const int c_tri[16][6] = {
    {-1,-1,-1,-1,-1,-1},{1,0,2,-1,-1,-1},{4,0,3,-1,-1,-1},{1,4,2,1,3,4},
    {3,1,5,-1,-1,-1},{2,3,0,2,5,3},{1,4,0,1,5,4},{4,2,5,-1,-1,-1},
    {4,5,2,-1,-1,-1},{4,1,0,4,5,1},{3,2,0,3,5,2},{1,3,5,-1,-1,-1},
    {4,1,2,4,3,1},{3,0,4,-1,-1,-1},{2,0,1,-1,-1,-1},{-1,-1,-1,-1,-1,-1}};
__device__ const int c_ntri[16] = {0,1,1,2,1,2,2,1,1,2,2,1,2,1,1,0};
__device__ const int c_edges[12] = {0,1,0,2,0,3,1,2,1,3,2,3};

// ---------------- generic exclusive scan (3 kernels) ----------------
#define SCAN_B 256
#define SCAN_I 8
#define SCAN_TILE (SCAN_B*SCAN_I)

__global__ void k_scan_partial(const int* __restrict__ in, int* __restrict__ partials, int n){
  __shared__ int sm[SCAN_B];
  int b = blockIdx.x;
  long long base = (long long)b*SCAN_TILE;
  int sum = 0;
  for (int i = threadIdx.x; i < SCAN_TILE; i += SCAN_B){
    long long idx = base + i;
    if (idx < n) sum += in[idx];
  }
  sm[threadIdx.x] = sum; __syncthreads();
  for (int s = SCAN_B/2; s > 0; s >>= 1){
    if ((int)threadIdx.x < s) sm[threadIdx.x] += sm[threadIdx.x + s];
    __syncthreads();
  }
  if (threadIdx.x == 0) partials[b] = sm[0];
}

__global__ void k_scan_blocksums(int* __restrict__ partials, int nb, int* __restrict__ total_out){
  __shared__ int sm[SCAN_B];
  int carry = 0;
  for (int base = 0; base < nb; base += SCAN_B){
    int i = base + (int)threadIdx.x;
    int v = (i < nb) ? partials[i] : 0;
    sm[threadIdx.x] = v; __syncthreads();
    for (int off = 1; off < SCAN_B; off <<= 1){
      int t = ((int)threadIdx.x >= off) ? sm[threadIdx.x - off] : 0;
      __syncthreads();
      sm[threadIdx.x] += t;
      __syncthreads();
    }
    if (i < nb) partials[i] = carry + sm[threadIdx.x] - v;  // exclusive
    int tilesum = sm[SCAN_B-1];
    __syncthreads();
    carry += tilesum;
  }
  if (threadIdx.x == 0 && total_out) *total_out = carry;
}

__global__ void k_scan_apply(const int* __restrict__ in, int* __restrict__ out,
                             const int* __restrict__ partials, int n){
  __shared__ int sm[SCAN_B];
  int b = blockIdx.x;
  long long base = (long long)b*SCAN_TILE + (long long)threadIdx.x*SCAN_I;
  int v[SCAN_I]; int s = 0;
  #pragma unroll
  for (int k = 0; k < SCAN_I; k++){ long long idx = base + k; v[k] = (idx < n) ? in[idx] : 0; s += v[k]; }
  sm[threadIdx.x] = s; __syncthreads();
  for (int off = 1; off < SCAN_B; off <<= 1){
    int t = ((int)threadIdx.x >= off) ? sm[threadIdx.x - off] : 0;
    __syncthreads();
    sm[threadIdx.x] += t;
    __syncthreads();
  }
  int excl = sm[threadIdx.x] - s + partials[b];
  #pragma unroll
  for (int k = 0; k < SCAN_I; k++){ long long idx = base + k; if (idx < n) out[idx] = excl; excl += v[k]; }
}

// ---------------- pipeline kernels ----------------
__global__ void k_zero(int* __restrict__ p, int n){
  int i = blockIdx.x*256 + threadIdx.x; if (i < n) p[i] = 0;
}

__global__ void k_copy(const int* __restrict__ src, int* __restrict__ dst, int n){
  int i = blockIdx.x*256 + threadIdx.x; if (i < n) dst[i] = src[i];
}

__global__ void k_classify(const int* __restrict__ tet, const float* __restrict__ sdf,
                           int* __restrict__ tetinfo, int* __restrict__ m1f, int* __restrict__ m2f,
                           int* __restrict__ bucketCnt){
  int t = blockIdx.x*256 + threadIdx.x; if (t >= kNT) return;
  int4 v4 = ((const int4*)tet)[t];
  int vv[4] = {v4.x, v4.y, v4.z, v4.w};
  int occ[4]; int pat = 0;
  #pragma unroll
  for (int i = 0; i < 4; i++){ occ[i] = (sdf[vv[i]] > 0.0f) ? 1 : 0; pat |= occ[i] << i; }
  tetinfo[t] = pat;
  int nt_ = c_ntri[pat];
  m1f[t] = (nt_ == 1) ? 1 : 0;
  m2f[t] = (nt_ == 2) ? 1 : 0;
  if (pat == 0 || pat == 15) return;
  #pragma unroll
  for (int e = 0; e < 6; e++){
    int i0 = c_edges[2*e], i1 = c_edges[2*e+1];
    if (occ[i0] != occ[i1]){
      int a = vv[i0], b = vv[i1];
      if (a > b){ int tm = a; a = b; b = tm; }
      atomicAdd(&bucketCnt[a], 1);
    }
  }
}

__global__ void k_fill(const int* __restrict__ tet, const float* __restrict__ sdf,
                       int* __restrict__ cursor, unsigned long long* __restrict__ ebuf){
  int t = blockIdx.x*256 + threadIdx.x; if (t >= kNT) return;
  int4 v4 = ((const int4*)tet)[t];
  int vv[4] = {v4.x, v4.y, v4.z, v4.w};
  int occ[4];
  #pragma unroll
  for (int i = 0; i < 4; i++) occ[i] = (sdf[vv[i]] > 0.0f) ? 1 : 0;
  #pragma unroll
  for (int e = 0; e < 6; e++){
    int i0 = c_edges[2*e], i1 = c_edges[2*e+1];
    if (occ[i0] != occ[i1]){
      int a = vv[i0], b = vv[i1];
      if (a > b){ int tm = a; a = b; b = tm; }
      int pos = atomicAdd(&cursor[a], 1);
      ebuf[pos] = ((unsigned long long)(unsigned)b << 23) | (unsigned)(t*6 + e);
    }
  }
}

// sort each bucket by packed (b,payload); count unique b per bucket
__global__ void k_sort(const int* __restrict__ bucketStart, unsigned long long* __restrict__ ebuf,
                       int* __restrict__ ucnt){
  int a = blockIdx.x*256 + threadIdx.x; if (a >= kNV) return;
  int s = bucketStart[a], e = bucketStart[a+1];
  for (int i = s+1; i < e; i++){
    unsigned long long key = ebuf[i];
    int j = i - 1;
    while (j >= s && ebuf[j] > key){ ebuf[j+1] = ebuf[j]; j--; }
    ebuf[j+1] = key;
  }
  int cnt = 0; long long prev = -1;
  for (int i = s; i < e; i++){
    int b = (int)(ebuf[i] >> 23);
    if (b != prev){ cnt++; prev = b; }
  }
  ucnt[a] = cnt;
}

// emit interpolated verts (sorted-unique order) + scatter ranks into idx_map
__global__ void k_emit(const int* __restrict__ bucketStart, const unsigned long long* __restrict__ ebuf,
                       const int* __restrict__ vertBase, const float* __restrict__ pos,
                       const float* __restrict__ sdf, float* __restrict__ out, int* __restrict__ idx_map){
  int a = blockIdx.x*256 + threadIdx.x; if (a >= kNV) return;
  int s = bucketStart[a], e = bucketStart[a+1];
  if (s == e) return;
  float sa = sdf[a];
  float pax = pos[3*a], pay = pos[3*a+1], paz = pos[3*a+2];
  int r = vertBase[a] - 1;
  long long prev = -1;
  for (int i = s; i < e; i++){
    unsigned long long p = ebuf[i];
    int b = (int)(p >> 23);
    int payload = (int)(p & 0x7FFFFFULL);
    if (b != prev){
      prev = b; r++;
      float sb = sdf[b];
      float denom = sa - sb;               // s = [sa, -sb]; denom = sa - sb (never 0 for crossing)
      float w0 = (-sb) / denom;            // w = [-sb, sa] / denom
      float w1 = sa / denom;
      out[3LL*r + 0] = pax*w0 + pos[3*b+0]*w1;
      out[3LL*r + 1] = pay*w0 + pos[3*b+1]*w1;
      out[3LL*r + 2] = paz*w0 + pos[3*b+2]*w1;
    }
    idx_map[payload] = r;
  }
}

__global__ void k_faces(const int* __restrict__ tetinfo, const int* __restrict__ m1scan,
                        const int* __restrict__ m2scan, const int* __restrict__ idx_map,
                        const int* __restrict__ vertBase, float* __restrict__ out){
  int t = blockIdx.x*256 + threadIdx.x; if (t >= kNT) return;
  int pat = tetinfo[t];
  int nt_ = c_ntri[pat];
  if (nt_ == 0) return;
  int Nm1 = m1scan[kNT], Nm2 = m2scan[kNT], Ne = vertBase[kNV];
  long long Nf = (long long)Nm1 + 2LL*Nm2;
  long long faces_off = 3LL*Ne;
  long long uvidx_off = faces_off + 3LL*Nf + UVS_FLOATS;
  for (int k = 0; k < nt_; k++){
    long long row = (nt_ == 1) ? (long long)m1scan[t] : ((long long)Nm1 + 2LL*m2scan[t] + k);
    #pragma unroll
    for (int c = 0; c < 3; c++){
      int slot = c_tri[pat][3*k + c];
      out[faces_off + 3*row + c] = (float)idx_map[6*t + slot];
    }
    // face_gidx = 2t (+k for 2-tri tets); uv rows [4t, 4t+tri+1, 4t+tri+2], exact in f32 (<2^24)
    out[uvidx_off + 3*row + 0] = (float)(4*t);
    out[uvidx_off + 3*row + 1] = (float)(4*t + k + 1);
    out[uvidx_off + 3*row + 2] = (float)(4*t + k + 2);
  }
}

__global__ void k_uvs(const int* __restrict__ m1scan, const int* __restrict__ m2scan,
                      const int* __restrict__ vertBase, float* __restrict__ out){
  long long r = (long long)blockIdx.x*256 + threadIdx.x;
  if (r >= UVS_ROWS) return;
  int Nm1 = m1scan[kNT], Nm2 = m2scan[kNT], Ne = vertBase[kNV];
  long long off = 3LL*Ne + 3LL*((long long)Nm1 + 2LL*Nm2);
  int cell = (int)(r >> 2), k = (int)(r & 3);
  int iy = cell / kNUV, ix = cell - iy*kNUV;
  const float delta = (1.0f - 1.0f/895.0f) / 894.0f;   // linspace(0, 1-1/N, N) step, f32
  const float pad = 0.9f / 895.0f;
  float x = (float)ix * delta, y = (float)iy * delta;
  float u = x + ((k == 1 || k == 2) ? pad : 0.0f);
  float v = y + ((k >= 2) ? pad : 0.0f);
  out[off + 2*r]     = u;
  out[off + 2*r + 1] = v;
}

// ---------------- host ----------------
static inline int divup(int a, int b){ return (a + b - 1) / b; }

static void run_scan(const int* in, int* out, int n, int* partials, hipStream_t s){
  int nb = (n + SCAN_TILE - 1) / SCAN_TILE;
  k_scan_partial<<<nb, SCAN_B, 0, s>>>(in, partials, n);
  k_scan_blocksums<<<1, SCAN_B, 0, s>>>(partials, nb, out + n);  // total -> out[n]
  k_scan_apply<<<nb, SCAN_B, 0, s>>>(in, out, partials, n);
}

extern "C" void kernel_launch(void* const* d_in, const int* in_sizes, int n_in,
                              void* d_out, int out_size, void* d_ws, size_t ws_size,
                              hipStream_t stream){
  const float* pos = (const float*)d_in[0];
  const float* sdf = (const float*)d_in[1];
  const int*   tet = (const int*)d_in[2];
  float* out = (float*)d_out;

  char* ws = (char*)d_ws;
  size_t off = 0;
  auto alloc = [&](size_t bytes) -> char* {
    char* p = ws + off; off += (bytes + 255) & ~(size_t)255; return p;
  };
  int* tetinfo    = (int*)alloc((size_t)kNT*4);
  int* m1f        = (int*)alloc((size_t)kNT*4);
  int* m2f        = (int*)alloc((size_t)kNT*4);
  int* m1scan     = (int*)alloc((size_t)(kNT+1)*4);
  int* m2scan     = (int*)alloc((size_t)(kNT+1)*4);
  int* bucketCnt  = (int*)alloc((size_t)kNV*4);
  int* bucketStart= (int*)alloc((size_t)(kNV+1)*4);
  int* cursor     = (int*)alloc((size_t)kNV*4);
  int* ucnt       = (int*)alloc((size_t)kNV*4);
  int* vertBase   = (int*)alloc((size_t)(kNV+1)*4);
  int* idx_map    = (int*)alloc((size_t)kNT*6*4);
  unsigned long long* ebuf = (unsigned long long*)alloc((size_t)CAP*8);
  int* partials   = (int*)alloc(4096*4);
  if (off > ws_size){
    fprintf(stderr, "[dmtet] workspace too small: need %zu have %zu\n", off, ws_size);
    return;
  }

  k_zero<<<divup(kNV,256), 256, 0, stream>>>(bucketCnt, kNV);
  k_classify<<<divup(kNT,256), 256, 0, stream>>>(tet, sdf, tetinfo, m1f, m2f, bucketCnt);
  run_scan(m1f, m1scan, kNT, partials, stream);
  run_scan(m2f, m2scan, kNT, partials, stream);
  run_scan(bucketCnt, bucketStart, kNV, partials, stream);
  k_copy<<<divup(kNV,256), 256, 0, stream>>>(bucketStart, cursor, kNV);
  k_fill<<<divup(kNT,256), 256, 0, stream>>>(tet, sdf, cursor, ebuf);
  k_sort<<<divup(kNV,256), 256, 0, stream>>>(bucketStart, ebuf, ucnt);
  run_scan(ucnt, vertBase, kNV, partials, stream);
  k_emit<<<divup(kNV,256), 256, 0, stream>>>(bucketStart, ebuf, vertBase, pos, sdf, out, idx_map);
  k_faces<<<divup(kNT,256), 256, 0, stream>>>(tetinfo, m1scan, m2scan, idx_map, vertBase, out);
  k_uvs<<<divup((int)UVS_ROWS,256), 256, 0, stream>>>(m1scan, m2scan, vertBase, out);
}

// Round 2
// 545.510 us; speedup vs baseline: 1.2410x; 1.2410x over previous
//
#include <hip/hip_runtime.h>
#include <cstdio>
#include <cstdint>

// ---------------- problem constants ----------------
static const int kNV = 200000;
static const int kNT = 800000;
static const int kNUV = 895;                       // ceil(sqrt((2*NT+1)//2))
#define UVS_ROWS   3204100LL                       // kNUV*kNUV*4
#define UVS_FLOATS 6408200LL                       // UVS_ROWS*2
#define CAP 3300000                                // max crossing-edge instances (<= 4*NT = 3.2M)

__device__ const int c_tri[16][6] = {
    {-1,-1,-1,-1,-1,-1},{1,0,2,-1,-1,-1},{4,0,3,-1,-1,-1},{1,4,2,1,3,4},
    {3,1,5,-1,-1,-1},{2,3,0,2,5,3},{1,4,0,1,5,4},{4,2,5,-1,-1,-1},
    {4,5,2,-1,-1,-1},{4,1,0,4,5,1},{3,2,0,3,5,2},{1,3,5,-1,-1,-1},
    {4,1,2,4,3,1},{3,0,4,-1,-1,-1},{2,0,1,-1,-1,-1},{-1,-1,-1,-1,-1,-1}};
__device__ const int c_ntri[16] = {0,1,1,2,1,2,2,1,1,2,2,1,2,1,1,0};
__device__ const int c_edges[12] = {0,1,0,2,0,3,1,2,1,3,2,3};

// ---------------- generic exclusive scan (3 kernels) ----------------
#define SCAN_B 256
#define SCAN_I 8
#define SCAN_TILE (SCAN_B*SCAN_I)

__global__ void k_scan_partial(const int* __restrict__ in, int* __restrict__ partials, int n){
  __shared__ int sm[SCAN_B];
  int b = blockIdx.x;
  long long base = (long long)b*SCAN_TILE;
  int sum = 0;
  for (int i = threadIdx.x; i < SCAN_TILE; i += SCAN_B){
    long long idx = base + i;
    if (idx < n) sum += in[idx];
  }
  sm[threadIdx.x] = sum; __syncthreads();
  for (int s = SCAN_B/2; s > 0; s >>= 1){
    if ((int)threadIdx.x < s) sm[threadIdx.x] += sm[threadIdx.x + s];
    __syncthreads();
  }
  if (threadIdx.x == 0) partials[b] = sm[0];
}

__global__ void k_scan_blocksums(int* __restrict__ partials, int nb, int* __restrict__ total_out){
  __shared__ int sm[SCAN_B];
  int carry = 0;
  for (int base = 0; base < nb; base += SCAN_B){
    int i = base + (int)threadIdx.x;
    int v = (i < nb) ? partials[i] : 0;
    sm[threadIdx.x] = v; __syncthreads();
    for (int off = 1; off < SCAN_B; off <<= 1){
      int t = ((int)threadIdx.x >= off) ? sm[threadIdx.x - off] : 0;
      __syncthreads();
      sm[threadIdx.x] += t;
      __syncthreads();
    }
    if (i < nb) partials[i] = carry + sm[threadIdx.x] - v;  // exclusive
    int tilesum = sm[SCAN_B-1];
    __syncthreads();
    carry += tilesum;
  }
  if (threadIdx.x == 0 && total_out) *total_out = carry;
}

__global__ void k_scan_apply(const int* __restrict__ in, int* __restrict__ out,
                             const int* __restrict__ partials, int n){
  __shared__ int sm[SCAN_B];
  int b = blockIdx.x;
  long long base = (long long)b*SCAN_TILE + (long long)threadIdx.x*SCAN_I;
  int v[SCAN_I]; int s = 0;
  #pragma unroll
  for (int k = 0; k < SCAN_I; k++){ long long idx = base + k; v[k] = (idx < n) ? in[idx] : 0; s += v[k]; }
  sm[threadIdx.x] = s; __syncthreads();
  for (int off = 1; off < SCAN_B; off <<= 1){
    int t = ((int)threadIdx.x >= off) ? sm[threadIdx.x - off] : 0;
    __syncthreads();
    sm[threadIdx.x] += t;
    __syncthreads();
  }
  int excl = sm[threadIdx.x] - s + partials[b];
  #pragma unroll
  for (int k = 0; k < SCAN_I; k++){ long long idx = base + k; if (idx < n) out[idx] = excl; excl += v[k]; }
}

// ---------------- pipeline kernels ----------------
__global__ void k_zero(int* __restrict__ p, int n){
  int i = blockIdx.x*256 + threadIdx.x; if (i < n) p[i] = 0;
}

__global__ void k_copy(const int* __restrict__ src, int* __restrict__ dst, int n){
  int i = blockIdx.x*256 + threadIdx.x; if (i < n) dst[i] = src[i];
}

__global__ void k_classify(const int* __restrict__ tet, const float* __restrict__ sdf,
                           int* __restrict__ tetinfo, int* __restrict__ m1f, int* __restrict__ m2f,
                           int* __restrict__ bucketCnt){
  int t = blockIdx.x*256 + threadIdx.x; if (t >= kNT) return;
  int4 v4 = ((const int4*)tet)[t];
  int vv[4] = {v4.x, v4.y, v4.z, v4.w};
  int occ[4]; int pat = 0;
  #pragma unroll
  for (int i = 0; i < 4; i++){ occ[i] = (sdf[vv[i]] > 0.0f) ? 1 : 0; pat |= occ[i] << i; }
  tetinfo[t] = pat;
  int nt_ = c_ntri[pat];
  m1f[t] = (nt_ == 1) ? 1 : 0;
  m2f[t] = (nt_ == 2) ? 1 : 0;
  if (pat == 0 || pat == 15) return;
  #pragma unroll
  for (int e = 0; e < 6; e++){
    int i0 = c_edges[2*e], i1 = c_edges[2*e+1];
    if (occ[i0] != occ[i1]){
      int a = vv[i0], b = vv[i1];
      if (a > b){ int tm = a; a = b; b = tm; }
      atomicAdd(&bucketCnt[a], 1);
    }
  }
}

__global__ void k_fill(const int* __restrict__ tet, const int* __restrict__ tetinfo,
                       int* __restrict__ cursor, unsigned long long* __restrict__ ebuf){
  int t = blockIdx.x*256 + threadIdx.x; if (t >= kNT) return;
  int pat = tetinfo[t];
  if (pat == 0 || pat == 15) return;
  int4 v4 = ((const int4*)tet)[t];
  int vv[4] = {v4.x, v4.y, v4.z, v4.w};
  #pragma unroll
  for (int e = 0; e < 6; e++){
    int i0 = c_edges[2*e], i1 = c_edges[2*e+1];
    if (((pat >> i0) & 1) != ((pat >> i1) & 1)){
      int a = vv[i0], b = vv[i1];
      if (a > b){ int tm = a; a = b; b = tm; }
      int pos = atomicAdd(&cursor[a], 1);
      ebuf[pos] = ((unsigned long long)(unsigned)b << 23) | (unsigned)(t*6 + e);
    }
  }
}

// wave-per-bucket: count distinct b values per bucket (no sort, no global writes)
__global__ void k_rank_count(const int* __restrict__ bucketStart,
                             unsigned long long* __restrict__ ebuf,
                             int* __restrict__ ucnt){
  int lane = threadIdx.x & 63;
  int a = blockIdx.x*4 + (threadIdx.x >> 6);
  if (a >= kNV) return;
  int s = bucketStart[a], e = bucketStart[a+1];
  int k = e - s;
  if (k == 0){ if (lane == 0) ucnt[a] = 0; return; }
  if (k <= 64){
    int val = (lane < k) ? (int)(ebuf[s + lane] >> 23) : 0x7FFFFFFF;
    bool first = (lane < k);
    for (int j = 0; j < k; j++){
      int vj = __shfl(val, j);
      if (j < lane && vj == val) first = false;
    }
    unsigned long long m = __ballot(first);
    if (lane == 0) ucnt[a] = __popcll(m);
  } else if (lane == 0){
    // fallback (statistically never): serial insertion sort + unique count
    for (int i = s+1; i < e; i++){
      unsigned long long key = ebuf[i];
      int j = i - 1;
      while (j >= s && ebuf[j] > key){ ebuf[j+1] = ebuf[j]; j--; }
      ebuf[j+1] = key;
    }
    int cnt = 0; long long prev = -1;
    for (int i = s; i < e; i++){
      int b = (int)(ebuf[i] >> 23);
      if (b != prev){ cnt++; prev = b; }
    }
    ucnt[a] = cnt;
  }
}

// wave-per-bucket: recompute ranks, emit verts (distinct edges) + idx_map (all instances)
__global__ void k_rank_emit(const int* __restrict__ bucketStart,
                            const unsigned long long* __restrict__ ebuf,
                            const int* __restrict__ vertBase, const float* __restrict__ pos,
                            const float* __restrict__ sdf, float* __restrict__ out,
                            int* __restrict__ idx_map){
  int lane = threadIdx.x & 63;
  int a = blockIdx.x*4 + (threadIdx.x >> 6);
  if (a >= kNV) return;
  int s = bucketStart[a], e = bucketStart[a+1];
  int k = e - s;
  if (k == 0) return;
  int base = vertBase[a];
  if (k <= 64){
    unsigned long long item = (lane < k) ? ebuf[s + lane] : ~0ULL;
    int val = (lane < k) ? (int)(item >> 23) : 0x7FFFFFFF;
    int payload = (int)(item & 0x7FFFFFULL);
    bool first = (lane < k);
    for (int j = 0; j < k; j++){
      int vj = __shfl(val, j);
      if (j < lane && vj == val) first = false;
    }
    unsigned long long m = __ballot(first);
    int rank = 0;
    for (int j = 0; j < k; j++){
      int vj = __shfl(val, j);
      if (((m >> j) & 1ULL) && vj < val) rank++;
    }
    if (lane < k){
      int r = base + rank;
      idx_map[payload] = r;
      if (first){
        int b = val;
        float sa = sdf[a], sb = sdf[b];
        float denom = sa - sb;               // s = [sa,-sb]; never 0 for a crossing edge
        float w0 = (-sb) / denom;
        float w1 = sa / denom;
        out[3LL*r + 0] = pos[3*a+0]*w0 + pos[3*b+0]*w1;
        out[3LL*r + 1] = pos[3*a+1]*w0 + pos[3*b+1]*w1;
        out[3LL*r + 2] = pos[3*a+2]*w0 + pos[3*b+2]*w1;
      }
    }
  } else if (lane == 0){
    // fallback: ebuf was sorted by k_rank_count's fallback
    float sa = sdf[a];
    float pax = pos[3*a], pay = pos[3*a+1], paz = pos[3*a+2];
    int r = base - 1;
    long long prev = -1;
    for (int i = s; i < e; i++){
      unsigned long long p = ebuf[i];
      int b = (int)(p >> 23);
      int payload = (int)(p & 0x7FFFFFULL);
      if (b != prev){
        prev = b; r++;
        float sb = sdf[b];
        float denom = sa - sb;
        float w0 = (-sb) / denom, w1 = sa / denom;
        out[3LL*r + 0] = pax*w0 + pos[3*b+0]*w1;
        out[3LL*r + 1] = pay*w0 + pos[3*b+1]*w1;
        out[3LL*r + 2] = paz*w0 + pos[3*b+2]*w1;
      }
      idx_map[payload] = r;
    }
  }
}

__global__ void k_faces(const int* __restrict__ tetinfo, const int* __restrict__ m1scan,
                        const int* __restrict__ m2scan, const int* __restrict__ idx_map,
                        const int* __restrict__ vertBase, float* __restrict__ out){
  int t = blockIdx.x*256 + threadIdx.x; if (t >= kNT) return;
  int pat = tetinfo[t];
  int nt_ = c_ntri[pat];
  if (nt_ == 0) return;
  int Nm1 = m1scan[kNT], Nm2 = m2scan[kNT], Ne = vertBase[kNV];
  long long Nf = (long long)Nm1 + 2LL*Nm2;
  long long faces_off = 3LL*Ne;
  long long uvidx_off = faces_off + 3LL*Nf + UVS_FLOATS;
  for (int k = 0; k < nt_; k++){
    long long row = (nt_ == 1) ? (long long)m1scan[t] : ((long long)Nm1 + 2LL*m2scan[t] + k);
    #pragma unroll
    for (int c = 0; c < 3; c++){
      int slot = c_tri[pat][3*k + c];
      out[faces_off + 3*row + c] = (float)idx_map[6*t + slot];
    }
    // face_gidx = 2t (+k); uv rows [4t, 4t+k+1, 4t+k+2], exact in f32 (<2^24)
    out[uvidx_off + 3*row + 0] = (float)(4*t);
    out[uvidx_off + 3*row + 1] = (float)(4*t + k + 1);
    out[uvidx_off + 3*row + 2] = (float)(4*t + k + 2);
  }
}

__global__ void k_uvs(const int* __restrict__ m1scan, const int* __restrict__ m2scan,
                      const int* __restrict__ vertBase, float* __restrict__ out){
  long long r = (long long)blockIdx.x*256 + threadIdx.x;
  if (r >= UVS_ROWS) return;
  int Nm1 = m1scan[kNT], Nm2 = m2scan[kNT], Ne = vertBase[kNV];
  long long off = 3LL*Ne + 3LL*((long long)Nm1 + 2LL*Nm2);
  int cell = (int)(r >> 2), k = (int)(r & 3);
  int iy = cell / kNUV, ix = cell - iy*kNUV;
  const float delta = (1.0f - 1.0f/895.0f) / 894.0f;   // linspace(0, 1-1/N, N) step, f32
  const float pad = 0.9f / 895.0f;
  float x = (float)ix * delta, y = (float)iy * delta;
  float u = x + ((k == 1 || k == 2) ? pad : 0.0f);
  float v = y + ((k >= 2) ? pad : 0.0f);
  out[off + 2*r]     = u;
  out[off + 2*r + 1] = v;
}

// ---------------- host ----------------
static inline int divup(int a, int b){ return (a + b - 1) / b; }

static void run_scan(const int* in, int* out, int n, int* partials, hipStream_t s){
  int nb = (n + SCAN_TILE - 1) / SCAN_TILE;
  k_scan_partial<<<nb, SCAN_B, 0, s>>>(in, partials, n);
  k_scan_blocksums<<<1, SCAN_B, 0, s>>>(partials, nb, out + n);  // total -> out[n]
  k_scan_apply<<<nb, SCAN_B, 0, s>>>(in, out, partials, n);
}

extern "C" void kernel_launch(void* const* d_in, const int* in_sizes, int n_in,
                              void* d_out, int out_size, void* d_ws, size_t ws_size,
                              hipStream_t stream){
  const float* pos = (const float*)d_in[0];
  const float* sdf = (const float*)d_in[1];
  const int*   tet = (const int*)d_in[2];
  float* out = (float*)d_out;

  char* ws = (char*)d_ws;
  size_t off = 0;
  auto alloc = [&](size_t bytes) -> char* {
    char* p = ws + off; off += (bytes + 255) & ~(size_t)255; return p;
  };
  int* tetinfo    = (int*)alloc((size_t)kNT*4);
  int* m1f        = (int*)alloc((size_t)kNT*4);
  int* m2f        = (int*)alloc((size_t)kNT*4);
  int* m1scan     = (int*)alloc((size_t)(kNT+1)*4);
  int* m2scan     = (int*)alloc((size_t)(kNT+1)*4);
  int* bucketCnt  = (int*)alloc((size_t)kNV*4);
  int* bucketStart= (int*)alloc((size_t)(kNV+1)*4);
  int* cursor     = (int*)alloc((size_t)kNV*4);
  int* ucnt       = (int*)alloc((size_t)kNV*4);
  int* vertBase   = (int*)alloc((size_t)(kNV+1)*4);
  int* idx_map    = (int*)alloc((size_t)kNT*6*4);
  unsigned long long* ebuf = (unsigned long long*)alloc((size_t)CAP*8);
  int* partials   = (int*)alloc(4096*4);
  if (off > ws_size){
    fprintf(stderr, "[dmtet] workspace too small: need %zu have %zu\n", off, ws_size);
    return;
  }

  k_zero<<<divup(kNV,256), 256, 0, stream>>>(bucketCnt, kNV);
  k_classify<<<divup(kNT,256), 256, 0, stream>>>(tet, sdf, tetinfo, m1f, m2f, bucketCnt);
  run_scan(m1f, m1scan, kNT, partials, stream);
  run_scan(m2f, m2scan, kNT, partials, stream);
  run_scan(bucketCnt, bucketStart, kNV, partials, stream);
  k_copy<<<divup(kNV,256), 256, 0, stream>>>(bucketStart, cursor, kNV);
  k_fill<<<divup(kNT,256), 256, 0, stream>>>(tet, tetinfo, cursor, ebuf);
  k_rank_count<<<divup(kNV,4), 256, 0, stream>>>(bucketStart, ebuf, ucnt);
  run_scan(ucnt, vertBase, kNV, partials, stream);
  k_rank_emit<<<divup(kNV,4), 256, 0, stream>>>(bucketStart, ebuf, vertBase, pos, sdf, out, idx_map);
  k_faces<<<divup(kNT,256), 256, 0, stream>>>(tetinfo, m1scan, m2scan, idx_map, vertBase, out);
  k_uvs<<<divup((int)UVS_ROWS,256), 256, 0, stream>>>(m1scan, m2scan, vertBase, out);
}

// Round 3
// 461.441 us; speedup vs baseline: 1.4671x; 1.1822x over previous
//
#include <hip/hip_runtime.h>
#include <cstdio>
#include <cstdint>

// ---------------- problem constants ----------------
static const int kNV = 200000;
static const int kNT = 800000;
static const int kNUV = 895;                       // ceil(sqrt((2*NT+1)//2))
#define UVS_ROWS   3204100LL                       // kNUV*kNUV*4
#define UVS_FLOATS 6408200LL                       // UVS_ROWS*2
#define CAP 3300000                                // max crossing-edge instances (<= 4*NT = 3.2M)

// counting-sort geometry
#define NH 98                                      // hist/scatter blocks (8192 tets each)
#define TILE_T 8192
#define BINW 512                                   // a-values per coarse bin
#define NBIN 391                                   // ceil(200000/512)

__device__ const int c_tri[16][6] = {
    {-1,-1,-1,-1,-1,-1},{1,0,2,-1,-1,-1},{4,0,3,-1,-1,-1},{1,4,2,1,3,4},
    {3,1,5,-1,-1,-1},{2,3,0,2,5,3},{1,4,0,1,5,4},{4,2,5,-1,-1,-1},
    {4,5,2,-1,-1,-1},{4,1,0,4,5,1},{3,2,0,3,5,2},{1,3,5,-1,-1,-1},
    {4,1,2,4,3,1},{3,0,4,-1,-1,-1},{2,0,1,-1,-1,-1},{-1,-1,-1,-1,-1,-1}};
__device__ const int c_ntri[16] = {0,1,1,2,1,2,2,1,1,2,2,1,2,1,1,0};
__device__ const int c_edges[12] = {0,1,0,2,0,3,1,2,1,3,2,3};

// ---------------- generic exclusive scan (templated, 3 kernels) ----------------
#define SCAN_B 256
#define SCAN_I 8
#define SCAN_TILE (SCAN_B*SCAN_I)

template<typename T>
__global__ void k_scan_partial(const T* __restrict__ in, T* __restrict__ partials, int n){
  __shared__ T sm[SCAN_B];
  int b = blockIdx.x;
  long long base = (long long)b*SCAN_TILE;
  T sum = 0;
  for (int i = threadIdx.x; i < SCAN_TILE; i += SCAN_B){
    long long idx = base + i;
    if (idx < n) sum += in[idx];
  }
  sm[threadIdx.x] = sum; __syncthreads();
  for (int s = SCAN_B/2; s > 0; s >>= 1){
    if ((int)threadIdx.x < s) sm[threadIdx.x] += sm[threadIdx.x + s];
    __syncthreads();
  }
  if (threadIdx.x == 0) partials[b] = sm[0];
}

template<typename T>
__global__ void k_scan_blocksums(T* __restrict__ partials, int nb, T* __restrict__ total_out){
  __shared__ T sm[SCAN_B];
  T carry = 0;
  for (int base = 0; base < nb; base += SCAN_B){
    int i = base + (int)threadIdx.x;
    T v = (i < nb) ? partials[i] : (T)0;
    sm[threadIdx.x] = v; __syncthreads();
    for (int off = 1; off < SCAN_B; off <<= 1){
      T t = ((int)threadIdx.x >= off) ? sm[threadIdx.x - off] : (T)0;
      __syncthreads();
      sm[threadIdx.x] += t;
      __syncthreads();
    }
    if (i < nb) partials[i] = carry + sm[threadIdx.x] - v;  // exclusive
    T tilesum = sm[SCAN_B-1];
    __syncthreads();
    carry += tilesum;
  }
  if (threadIdx.x == 0 && total_out) *total_out = carry;
}

template<typename T>
__global__ void k_scan_apply(const T* __restrict__ in, T* __restrict__ out,
                             const T* __restrict__ partials, int n){
  __shared__ T sm[SCAN_B];
  int b = blockIdx.x;
  long long base = (long long)b*SCAN_TILE + (long long)threadIdx.x*SCAN_I;
  T v[SCAN_I]; T s = 0;
  #pragma unroll
  for (int k = 0; k < SCAN_I; k++){ long long idx = base + k; v[k] = (idx < n) ? in[idx] : (T)0; s += v[k]; }
  sm[threadIdx.x] = s; __syncthreads();
  for (int off = 1; off < SCAN_B; off <<= 1){
    T t = ((int)threadIdx.x >= off) ? sm[threadIdx.x - off] : (T)0;
    __syncthreads();
    sm[threadIdx.x] += t;
    __syncthreads();
  }
  T excl = sm[threadIdx.x] - s + partials[b];
  #pragma unroll
  for (int k = 0; k < SCAN_I; k++){ long long idx = base + k; if (idx < n) out[idx] = excl; excl += v[k]; }
}

template<typename T>
static void run_scan(const T* in, T* out, int n, T* partials, hipStream_t s){
  int nb = (n + SCAN_TILE - 1) / SCAN_TILE;
  k_scan_partial<T><<<nb, SCAN_B, 0, s>>>(in, partials, n);
  k_scan_blocksums<T><<<1, SCAN_B, 0, s>>>(partials, nb, out + n);  // total -> out[n]
  k_scan_apply<T><<<nb, SCAN_B, 0, s>>>(in, out, partials, n);
}

// ---------------- pipeline kernels ----------------

// per-tet: occupancy pattern + packed (m1,m2) flags for one fused scan
__global__ void k_classify(const int* __restrict__ tet, const float* __restrict__ sdf,
                           int* __restrict__ tetinfo, unsigned long long* __restrict__ pk){
  int t = blockIdx.x*256 + threadIdx.x; if (t >= kNT) return;
  int4 v4 = ((const int4*)tet)[t];
  int pat = ((sdf[v4.x] > 0.0f) ? 1 : 0) | ((sdf[v4.y] > 0.0f) ? 2 : 0)
          | ((sdf[v4.z] > 0.0f) ? 4 : 0) | ((sdf[v4.w] > 0.0f) ? 8 : 0);
  tetinfo[t] = pat;
  int nt_ = c_ntri[pat];
  pk[t] = ((unsigned long long)(nt_ == 1) << 32) | (unsigned)(nt_ == 2);
}

// pass 1 of counting sort: per-block LDS histogram of coarse bin (a>>9)
__global__ void k_hist(const int* __restrict__ tet, const int* __restrict__ tetinfo,
                       int* __restrict__ blockHist){
  __shared__ int h[NBIN];
  int blk = blockIdx.x;
  for (int j = threadIdx.x; j < NBIN; j += 256) h[j] = 0;
  __syncthreads();
  int t0 = blk*TILE_T;
  for (int k = 0; k < TILE_T/256; k++){
    int t = t0 + k*256 + threadIdx.x;
    if (t < kNT){
      int pat = tetinfo[t];
      if (pat != 0 && pat != 15){
        int4 v4 = ((const int4*)tet)[t];
        int vv[4] = {v4.x, v4.y, v4.z, v4.w};
        #pragma unroll
        for (int e = 0; e < 6; e++){
          int i0 = c_edges[2*e], i1 = c_edges[2*e+1];
          if (((pat >> i0) & 1) != ((pat >> i1) & 1)){
            int a = vv[i0], b = vv[i1]; if (a > b){ int tm = a; a = b; b = tm; }
            atomicAdd(&h[a >> 9], 1);
          }
        }
      }
    }
  }
  __syncthreads();
  for (int j = threadIdx.x; j < NBIN; j += 256) blockHist[j*NH + blk] = h[j];  // bin-major for scan
}

// pass 2: scatter instances to bin-grouped buffer via LDS cursors (no global atomics)
__global__ void k_scatter(const int* __restrict__ tet, const int* __restrict__ tetinfo,
                          const int* __restrict__ bhScan, unsigned long long* __restrict__ ebin){
  __shared__ int c[NBIN];
  int blk = blockIdx.x;
  for (int j = threadIdx.x; j < NBIN; j += 256) c[j] = bhScan[j*NH + blk];
  __syncthreads();
  int t0 = blk*TILE_T;
  for (int k = 0; k < TILE_T/256; k++){
    int t = t0 + k*256 + threadIdx.x;
    if (t < kNT){
      int pat = tetinfo[t];
      if (pat != 0 && pat != 15){
        int4 v4 = ((const int4*)tet)[t];
        int vv[4] = {v4.x, v4.y, v4.z, v4.w};
        #pragma unroll
        for (int e = 0; e < 6; e++){
          int i0 = c_edges[2*e], i1 = c_edges[2*e+1];
          if (((pat >> i0) & 1) != ((pat >> i1) & 1)){
            int a = vv[i0], b = vv[i1]; if (a > b){ int tm = a; a = b; b = tm; }
            int pos = atomicAdd(&c[a >> 9], 1);
            ebin[pos] = ((unsigned long long)(unsigned)a << 41)
                      | ((unsigned long long)(unsigned)b << 23)
                      | (unsigned)(t*6 + e);
          }
        }
      }
    }
  }
}

// pass 3: per coarse bin (L2-resident window): exact-a regroup + bucketStart
__global__ void k_fine(const int* __restrict__ bhScan, const unsigned long long* __restrict__ ebin,
                       unsigned long long* __restrict__ efin, int* __restrict__ bucketStart){
  __shared__ int h[BINW];
  __shared__ int ss[256];
  int bin = blockIdx.x;
  int binStart = bhScan[bin*NH];
  int binEnd   = bhScan[(bin+1)*NH];     // == total for bin == NBIN-1 (scan stores total at [n])
  int a0 = bin << 9;
  for (int j = threadIdx.x; j < BINW; j += 256) h[j] = 0;
  __syncthreads();
  for (int i = binStart + threadIdx.x; i < binEnd; i += 256){
    int a = (int)(ebin[i] >> 41);
    atomicAdd(&h[a - a0], 1);
  }
  __syncthreads();
  // exclusive scan of h[512] with 256 threads (2 elements each)
  int tid = threadIdx.x;
  int s0 = h[2*tid], s1 = h[2*tid+1];
  int pair = s0 + s1;
  ss[tid] = pair; __syncthreads();
  for (int off = 1; off < 256; off <<= 1){
    int v = (tid >= off) ? ss[tid - off] : 0;
    __syncthreads();
    ss[tid] += v;
    __syncthreads();
  }
  int excl = ss[tid] - pair;
  h[2*tid] = excl; h[2*tid+1] = excl + s0;
  __syncthreads();
  for (int j = tid; j < BINW; j += 256){
    int a = a0 + j;
    if (a < kNV) bucketStart[a] = binStart + h[j];
  }
  if (bin == NBIN-1 && tid == 0) bucketStart[kNV] = binEnd;
  __syncthreads();
  // regroup: h now serves as per-a cursors (exclusive offsets)
  for (int i = binStart + tid; i < binEnd; i += 256){
    unsigned long long p = ebin[i];
    int j = (int)(p >> 41) - a0;
    int pos = binStart + atomicAdd(&h[j], 1);
    efin[pos] = p;
  }
}

// wave-per-bucket: count distinct b values per bucket
__global__ void k_rank_count(const int* __restrict__ bucketStart,
                             unsigned long long* __restrict__ ebuf,
                             int* __restrict__ ucnt){
  int lane = threadIdx.x & 63;
  int a = blockIdx.x*4 + (threadIdx.x >> 6);
  if (a >= kNV) return;
  int s = bucketStart[a], e = bucketStart[a+1];
  int k = e - s;
  if (k == 0){ if (lane == 0) ucnt[a] = 0; return; }
  if (k <= 64){
    int val = (lane < k) ? (int)((ebuf[s + lane] >> 23) & 0x3FFFF) : 0x7FFFFFFF;
    bool first = (lane < k);
    for (int j = 0; j < k; j++){
      int vj = __shfl(val, j);
      if (j < lane && vj == val) first = false;
    }
    unsigned long long m = __ballot(first);
    if (lane == 0) ucnt[a] = __popcll(m);
  } else if (lane == 0){
    // fallback (statistically never): serial insertion sort + unique count
    for (int i = s+1; i < e; i++){
      unsigned long long key = ebuf[i];
      int j = i - 1;
      while (j >= s && ebuf[j] > key){ ebuf[j+1] = ebuf[j]; j--; }
      ebuf[j+1] = key;
    }
    int cnt = 0; long long prev = -1;
    for (int i = s; i < e; i++){
      int b = (int)((ebuf[i] >> 23) & 0x3FFFF);
      if (b != prev){ cnt++; prev = b; }
    }
    ucnt[a] = cnt;
  }
}

// wave-per-bucket: emit verts + sorted distinct-b list (edge_b) per bucket
__global__ void k_rank_emit(const int* __restrict__ bucketStart,
                            const unsigned long long* __restrict__ ebuf,
                            const int* __restrict__ vertBase, const float* __restrict__ pos,
                            const float* __restrict__ sdf, float* __restrict__ out,
                            int* __restrict__ edge_b){
  int lane = threadIdx.x & 63;
  int a = blockIdx.x*4 + (threadIdx.x >> 6);
  if (a >= kNV) return;
  int s = bucketStart[a], e = bucketStart[a+1];
  int k = e - s;
  if (k == 0) return;
  int base = vertBase[a];
  if (k <= 64){
    int val = (lane < k) ? (int)((ebuf[s + lane] >> 23) & 0x3FFFF) : 0x7FFFFFFF;
    bool first = (lane < k);
    for (int j = 0; j < k; j++){
      int vj = __shfl(val, j);
      if (j < lane && vj == val) first = false;
    }
    unsigned long long m = __ballot(first);
    int rank = 0;
    for (int j = 0; j < k; j++){
      int vj = __shfl(val, j);
      if (((m >> j) & 1ULL) && vj < val) rank++;
    }
    if (first){
      int r = base + rank;
      int b = val;
      edge_b[r] = b;
      float sa = sdf[a], sb = sdf[b];
      float denom = sa - sb;               // s = [sa,-sb]; never 0 for a crossing edge
      float w0 = (-sb) / denom;
      float w1 = sa / denom;
      out[3LL*r + 0] = pos[3*a+0]*w0 + pos[3*b+0]*w1;
      out[3LL*r + 1] = pos[3*a+1]*w0 + pos[3*b+1]*w1;
      out[3LL*r + 2] = pos[3*a+2]*w0 + pos[3*b+2]*w1;
    }
  } else if (lane == 0){
    // fallback: ebuf was sorted by k_rank_count's fallback
    float sa = sdf[a];
    float pax = pos[3*a], pay = pos[3*a+1], paz = pos[3*a+2];
    int r = base - 1;
    long long prev = -1;
    for (int i = s; i < e; i++){
      unsigned long long p = ebuf[i];
      int b = (int)((p >> 23) & 0x3FFFF);
      if (b != prev){
        prev = b; r++;
        edge_b[r] = b;
        float sb = sdf[b];
        float denom = sa - sb;
        float w0 = (-sb) / denom, w1 = sa / denom;
        out[3LL*r + 0] = pax*w0 + pos[3*b+0]*w1;
        out[3LL*r + 1] = pay*w0 + pos[3*b+1]*w1;
        out[3LL*r + 2] = paz*w0 + pos[3*b+2]*w1;
      }
    }
  }
}

// faces + uv_idx: recover vertex ranks by searching the sorted per-bucket edge_b list
__global__ void k_faces(const int* __restrict__ tet, const int* __restrict__ tetinfo,
                        const unsigned long long* __restrict__ psum,
                        const int* __restrict__ vertBase, const int* __restrict__ edge_b,
                        float* __restrict__ out){
  int t = blockIdx.x*256 + threadIdx.x; if (t >= kNT) return;
  int pat = tetinfo[t];
  int nt_ = c_ntri[pat];
  if (nt_ == 0) return;
  unsigned long long tot = psum[kNT];
  int Nm1 = (int)(tot >> 32), Nm2 = (int)(tot & 0xFFFFFFFFULL);
  int Ne = vertBase[kNV];
  long long faces_off = 3LL*Ne;
  long long uvidx_off = faces_off + 3LL*((long long)Nm1 + 2LL*Nm2) + UVS_FLOATS;
  unsigned long long ps = psum[t];
  int m1v = (int)(ps >> 32), m2v = (int)(ps & 0xFFFFFFFFULL);
  int4 v4 = ((const int4*)tet)[t];
  int vv[4] = {v4.x, v4.y, v4.z, v4.w};
  int er[6];
  #pragma unroll
  for (int e = 0; e < 6; e++){
    int i0 = c_edges[2*e], i1 = c_edges[2*e+1];
    if (((pat >> i0) & 1) != ((pat >> i1) & 1)){
      int a = vv[i0], b = vv[i1]; if (a > b){ int tm = a; a = b; b = tm; }
      int r = vertBase[a];
      while (edge_b[r] != b) r++;     // guaranteed present; avg ~6 cached reads
      er[e] = r;
    } else er[e] = -1;
  }
  for (int k = 0; k < nt_; k++){
    long long row = (nt_ == 1) ? (long long)m1v : ((long long)Nm1 + 2LL*m2v + k);
    #pragma unroll
    for (int c = 0; c < 3; c++){
      int slot = c_tri[pat][3*k + c];
      out[faces_off + 3*row + c] = (float)er[slot];
    }
    out[uvidx_off + 3*row + 0] = (float)(4*t);
    out[uvidx_off + 3*row + 1] = (float)(4*t + k + 1);
    out[uvidx_off + 3*row + 2] = (float)(4*t + k + 2);
  }
}

__global__ void k_uvs(const unsigned long long* __restrict__ psum,
                      const int* __restrict__ vertBase, float* __restrict__ out){
  long long r = (long long)blockIdx.x*256 + threadIdx.x;
  if (r >= UVS_ROWS) return;
  unsigned long long tot = psum[kNT];
  int Nm1 = (int)(tot >> 32), Nm2 = (int)(tot & 0xFFFFFFFFULL);
  int Ne = vertBase[kNV];
  long long off = 3LL*Ne + 3LL*((long long)Nm1 + 2LL*Nm2);
  int cell = (int)(r >> 2), k = (int)(r & 3);
  int iy = cell / kNUV, ix = cell - iy*kNUV;
  const float delta = (1.0f - 1.0f/895.0f) / 894.0f;   // linspace(0, 1-1/N, N) step, f32
  const float pad = 0.9f / 895.0f;
  float x = (float)ix * delta, y = (float)iy * delta;
  float u = x + ((k == 1 || k == 2) ? pad : 0.0f);
  float v = y + ((k >= 2) ? pad : 0.0f);
  out[off + 2*r]     = u;
  out[off + 2*r + 1] = v;
}

// ---------------- host ----------------
static inline int divup(int a, int b){ return (a + b - 1) / b; }

extern "C" void kernel_launch(void* const* d_in, const int* in_sizes, int n_in,
                              void* d_out, int out_size, void* d_ws, size_t ws_size,
                              hipStream_t stream){
  const float* pos = (const float*)d_in[0];
  const float* sdf = (const float*)d_in[1];
  const int*   tet = (const int*)d_in[2];
  float* out = (float*)d_out;

  char* ws = (char*)d_ws;
  size_t off = 0;
  auto alloc = [&](size_t bytes) -> char* {
    char* p = ws + off; off += (bytes + 255) & ~(size_t)255; return p;
  };
  int* tetinfo                = (int*)alloc((size_t)kNT*4);
  unsigned long long* pk      = (unsigned long long*)alloc((size_t)kNT*8);
  unsigned long long* psum    = (unsigned long long*)alloc((size_t)(kNT+1)*8);
  int* blockHist              = (int*)alloc((size_t)NBIN*NH*4);
  int* bhScan                 = (int*)alloc((size_t)(NBIN*NH+1)*4);
  int* bucketStart            = (int*)alloc((size_t)(kNV+1)*4);
  int* ucnt                   = (int*)alloc((size_t)kNV*4);
  int* vertBase               = (int*)alloc((size_t)(kNV+1)*4);
  unsigned long long* ebin    = (unsigned long long*)alloc((size_t)CAP*8);
  unsigned long long* efin    = (unsigned long long*)alloc((size_t)CAP*8);
  int* edge_b                 = (int*)alloc((size_t)CAP*4);
  unsigned long long* part64  = (unsigned long long*)alloc(4096*8);
  int* partI                  = (int*)alloc(4096*4);
  if (off > ws_size){
    fprintf(stderr, "[dmtet] workspace too small: need %zu have %zu\n", off, ws_size);
    return;
  }

  k_classify<<<divup(kNT,256), 256, 0, stream>>>(tet, sdf, tetinfo, pk);
  run_scan<unsigned long long>(pk, psum, kNT, part64, stream);
  k_hist<<<NH, 256, 0, stream>>>(tet, tetinfo, blockHist);
  run_scan<int>(blockHist, bhScan, NBIN*NH, partI, stream);
  k_scatter<<<NH, 256, 0, stream>>>(tet, tetinfo, bhScan, ebin);
  k_fine<<<NBIN, 256, 0, stream>>>(bhScan, ebin, efin, bucketStart);
  k_rank_count<<<divup(kNV,4), 256, 0, stream>>>(bucketStart, efin, ucnt);
  run_scan<int>(ucnt, vertBase, kNV, partI, stream);
  k_rank_emit<<<divup(kNV,4), 256, 0, stream>>>(bucketStart, efin, vertBase, pos, sdf, out, edge_b);
  k_faces<<<divup(kNT,256), 256, 0, stream>>>(tet, tetinfo, psum, vertBase, edge_b, out);
  k_uvs<<<divup((int)UVS_ROWS,256), 256, 0, stream>>>(psum, vertBase, out);
}

// Round 4
// 402.690 us; speedup vs baseline: 1.6811x; 1.1459x over previous
//
#include <hip/hip_runtime.h>
#include <cstdio>
#include <cstdint>

// ---------------- problem constants ----------------
static const int kNV = 200000;
static const int kNT = 800000;
static const int kNUV = 895;                       // ceil(sqrt((2*NT+1)//2))
#define UVS_ROWS   3204100LL                       // kNUV*kNUV*4
#define UVS_FLOATS 6408200LL                       // UVS_ROWS*2
#define CAP 3300000                                // max crossing-edge instances (<= 4*NT = 3.2M)

// counting-sort geometry
#define NH 98                                      // hist/scatter blocks (8192 tets each)
#define TILE_T 8192
#define BINW 512                                   // a-values per coarse bin
#define NBIN 391                                   // ceil(200000/512)

__device__ const int c_tri[16][6] = {
    {-1,-1,-1,-1,-1,-1},{1,0,2,-1,-1,-1},{4,0,3,-1,-1,-1},{1,4,2,1,3,4},
    {3,1,5,-1,-1,-1},{2,3,0,2,5,3},{1,4,0,1,5,4},{4,2,5,-1,-1,-1},
    {4,5,2,-1,-1,-1},{4,1,0,4,5,1},{3,2,0,3,5,2},{1,3,5,-1,-1,-1},
    {4,1,2,4,3,1},{3,0,4,-1,-1,-1},{2,0,1,-1,-1,-1},{-1,-1,-1,-1,-1,-1}};
__device__ const int c_ntri[16]   = {0,1,1,2,1,2,2,1,1,2,2,1,2,1,1,0};
__device__ const int c_ncross[16] = {0,3,3,4,3,4,4,3,3,4,4,3,4,3,3,0};
__device__ const int c_edges[12] = {0,1,0,2,0,3,1,2,1,3,2,3};

// psum packing: m1 <<44 | m2 <<24 | ncross (m1,m2 totals < 2^20, ncross total < 2^24)
#define PK(m1,m2,nc) (((unsigned long long)(m1) << 44) | ((unsigned long long)(m2) << 24) | (unsigned long long)(nc))
// ebin packing: a <<40 | b <<22 | seq (a,b < 2^18, seq < 2^22)
#define EB_A(p)   ((int)((p) >> 40))
#define EB_B(p)   ((int)(((p) >> 22) & 0x3FFFF))
#define EB_SEQ(p) ((int)((p) & 0x3FFFFF))

// ---------------- generic exclusive scan (templated, 3 kernels) ----------------
#define SCAN_B 256
#define SCAN_I 8
#define SCAN_TILE (SCAN_B*SCAN_I)

template<typename T>
__global__ void k_scan_partial(const T* __restrict__ in, T* __restrict__ partials, int n){
  __shared__ T sm[SCAN_B];
  int b = blockIdx.x;
  long long base = (long long)b*SCAN_TILE;
  T sum = 0;
  for (int i = threadIdx.x; i < SCAN_TILE; i += SCAN_B){
    long long idx = base + i;
    if (idx < n) sum += in[idx];
  }
  sm[threadIdx.x] = sum; __syncthreads();
  for (int s = SCAN_B/2; s > 0; s >>= 1){
    if ((int)threadIdx.x < s) sm[threadIdx.x] += sm[threadIdx.x + s];
    __syncthreads();
  }
  if (threadIdx.x == 0) partials[b] = sm[0];
}

template<typename T>
__global__ void k_scan_blocksums(T* __restrict__ partials, int nb, T* __restrict__ total_out){
  __shared__ T sm[SCAN_B];
  T carry = 0;
  for (int base = 0; base < nb; base += SCAN_B){
    int i = base + (int)threadIdx.x;
    T v = (i < nb) ? partials[i] : (T)0;
    sm[threadIdx.x] = v; __syncthreads();
    for (int off = 1; off < SCAN_B; off <<= 1){
      T t = ((int)threadIdx.x >= off) ? sm[threadIdx.x - off] : (T)0;
      __syncthreads();
      sm[threadIdx.x] += t;
      __syncthreads();
    }
    if (i < nb) partials[i] = carry + sm[threadIdx.x] - v;  // exclusive
    T tilesum = sm[SCAN_B-1];
    __syncthreads();
    carry += tilesum;
  }
  if (threadIdx.x == 0 && total_out) *total_out = carry;
}

template<typename T>
__global__ void k_scan_apply(const T* __restrict__ in, T* __restrict__ out,
                             const T* __restrict__ partials, int n){
  __shared__ T sm[SCAN_B];
  int b = blockIdx.x;
  long long base = (long long)b*SCAN_TILE + (long long)threadIdx.x*SCAN_I;
  T v[SCAN_I]; T s = 0;
  #pragma unroll
  for (int k = 0; k < SCAN_I; k++){ long long idx = base + k; v[k] = (idx < n) ? in[idx] : (T)0; s += v[k]; }
  sm[threadIdx.x] = s; __syncthreads();
  for (int off = 1; off < SCAN_B; off <<= 1){
    T t = ((int)threadIdx.x >= off) ? sm[threadIdx.x - off] : (T)0;
    __syncthreads();
    sm[threadIdx.x] += t;
    __syncthreads();
  }
  T excl = sm[threadIdx.x] - s + partials[b];
  #pragma unroll
  for (int k = 0; k < SCAN_I; k++){ long long idx = base + k; if (idx < n) out[idx] = excl; excl += v[k]; }
}

template<typename T>
static void run_scan(const T* in, T* out, int n, T* partials, hipStream_t s){
  int nb = (n + SCAN_TILE - 1) / SCAN_TILE;
  k_scan_partial<T><<<nb, SCAN_B, 0, s>>>(in, partials, n);
  k_scan_blocksums<T><<<1, SCAN_B, 0, s>>>(partials, nb, out + n);  // total -> out[n]
  k_scan_apply<T><<<nb, SCAN_B, 0, s>>>(in, out, partials, n);
}

// ---------------- pipeline kernels ----------------

// per-tet: occupancy pattern + packed (m1,m2,ncross) for one fused scan
__global__ void k_classify(const int* __restrict__ tet, const float* __restrict__ sdf,
                           int* __restrict__ tetinfo, unsigned long long* __restrict__ pk){
  int t = blockIdx.x*256 + threadIdx.x; if (t >= kNT) return;
  int4 v4 = ((const int4*)tet)[t];
  int pat = ((sdf[v4.x] > 0.0f) ? 1 : 0) | ((sdf[v4.y] > 0.0f) ? 2 : 0)
          | ((sdf[v4.z] > 0.0f) ? 4 : 0) | ((sdf[v4.w] > 0.0f) ? 8 : 0);
  tetinfo[t] = pat;
  int nt_ = c_ntri[pat];
  pk[t] = PK(nt_ == 1, nt_ == 2, c_ncross[pat]);
}

// pass 1 of counting sort: per-block LDS histogram of coarse bin (a>>9)
__global__ void k_hist(const int* __restrict__ tet, const int* __restrict__ tetinfo,
                       int* __restrict__ blockHist){
  __shared__ int h[NBIN];
  int blk = blockIdx.x;
  for (int j = threadIdx.x; j < NBIN; j += 256) h[j] = 0;
  __syncthreads();
  int t0 = blk*TILE_T;
  for (int k = 0; k < TILE_T/256; k++){
    int t = t0 + k*256 + threadIdx.x;
    if (t < kNT){
      int pat = tetinfo[t];
      if (pat != 0 && pat != 15){
        int4 v4 = ((const int4*)tet)[t];
        int vv[4] = {v4.x, v4.y, v4.z, v4.w};
        #pragma unroll
        for (int e = 0; e < 6; e++){
          int i0 = c_edges[2*e], i1 = c_edges[2*e+1];
          if (((pat >> i0) & 1) != ((pat >> i1) & 1)){
            int a = vv[i0], b = vv[i1]; if (a > b){ int tm = a; a = b; b = tm; }
            atomicAdd(&h[a >> 9], 1);
          }
        }
      }
    }
  }
  __syncthreads();
  for (int j = threadIdx.x; j < NBIN; j += 256) blockHist[j*NH + blk] = h[j];  // bin-major for scan
}

// pass 2: scatter instances to bin-grouped buffer via LDS cursors; record dest[seq]
__global__ void k_scatter(const int* __restrict__ tet, const int* __restrict__ tetinfo,
                          const unsigned long long* __restrict__ psum,
                          const int* __restrict__ bhScan,
                          unsigned long long* __restrict__ ebin, int* __restrict__ dest){
  __shared__ int c[NBIN];
  int blk = blockIdx.x;
  for (int j = threadIdx.x; j < NBIN; j += 256) c[j] = bhScan[j*NH + blk];
  __syncthreads();
  int t0 = blk*TILE_T;
  for (int k = 0; k < TILE_T/256; k++){
    int t = t0 + k*256 + threadIdx.x;
    if (t < kNT){
      int pat = tetinfo[t];
      if (pat != 0 && pat != 15){
        int4 v4 = ((const int4*)tet)[t];
        int vv[4] = {v4.x, v4.y, v4.z, v4.w};
        int seq = (int)(psum[t] & 0xFFFFFF);
        #pragma unroll
        for (int e = 0; e < 6; e++){
          int i0 = c_edges[2*e], i1 = c_edges[2*e+1];
          if (((pat >> i0) & 1) != ((pat >> i1) & 1)){
            int a = vv[i0], b = vv[i1]; if (a > b){ int tm = a; a = b; b = tm; }
            int pos = atomicAdd(&c[a >> 9], 1);
            ebin[pos] = ((unsigned long long)(unsigned)a << 40)
                      | ((unsigned long long)(unsigned)b << 22)
                      | (unsigned)seq;
            dest[seq] = pos;
            seq++;
          }
        }
      }
    }
  }
}

// pass 3: per coarse bin: exact-a regroup + bucketStart + posmap (binpos -> finalpos)
__global__ void k_fine(const int* __restrict__ bhScan, const unsigned long long* __restrict__ ebin,
                       unsigned long long* __restrict__ efin, int* __restrict__ bucketStart,
                       int* __restrict__ posmap){
  __shared__ int h[BINW];
  __shared__ int ss[256];
  int bin = blockIdx.x;
  int binStart = bhScan[bin*NH];
  int binEnd   = bhScan[(bin+1)*NH];     // scan stores total at [n] for the last bin
  int a0 = bin << 9;
  for (int j = threadIdx.x; j < BINW; j += 256) h[j] = 0;
  __syncthreads();
  for (int i = binStart + threadIdx.x; i < binEnd; i += 256){
    int a = EB_A(ebin[i]);
    atomicAdd(&h[a - a0], 1);
  }
  __syncthreads();
  // exclusive scan of h[512] with 256 threads (2 elements each)
  int tid = threadIdx.x;
  int s0 = h[2*tid], s1 = h[2*tid+1];
  int pair = s0 + s1;
  ss[tid] = pair; __syncthreads();
  for (int off = 1; off < 256; off <<= 1){
    int v = (tid >= off) ? ss[tid - off] : 0;
    __syncthreads();
    ss[tid] += v;
    __syncthreads();
  }
  int excl = ss[tid] - pair;
  h[2*tid] = excl; h[2*tid+1] = excl + s0;
  __syncthreads();
  for (int j = tid; j < BINW; j += 256){
    int a = a0 + j;
    if (a < kNV) bucketStart[a] = binStart + h[j];
  }
  if (bin == NBIN-1 && tid == 0) bucketStart[kNV] = binEnd;
  __syncthreads();
  // regroup: h now serves as per-a cursors (exclusive offsets)
  for (int i = binStart + tid; i < binEnd; i += 256){
    unsigned long long p = ebin[i];
    int j = EB_A(p) - a0;
    int pos = binStart + atomicAdd(&h[j], 1);
    efin[pos] = p;
    posmap[i] = pos;
  }
}

// wave-per-bucket: count distinct b values per bucket
__global__ void k_rank_count(const int* __restrict__ bucketStart,
                             unsigned long long* __restrict__ ebuf,
                             int* __restrict__ ucnt){
  int lane = threadIdx.x & 63;
  int a = blockIdx.x*4 + (threadIdx.x >> 6);
  if (a >= kNV) return;
  int s = bucketStart[a], e = bucketStart[a+1];
  int k = e - s;
  if (k == 0){ if (lane == 0) ucnt[a] = 0; return; }
  if (k <= 64){
    int val = (lane < k) ? EB_B(ebuf[s + lane]) : 0x7FFFFFFF;
    bool first = (lane < k);
    for (int j = 0; j < k; j++){
      int vj = __shfl(val, j);
      if (j < lane && vj == val) first = false;
    }
    unsigned long long m = __ballot(first);
    if (lane == 0) ucnt[a] = __popcll(m);
  } else if (lane == 0){
    // fallback (statistically never): serial insertion sort + unique count
    for (int i = s+1; i < e; i++){
      unsigned long long key = ebuf[i];
      int j = i - 1;
      while (j >= s && ebuf[j] > key){ ebuf[j+1] = ebuf[j]; j--; }
      ebuf[j+1] = key;
    }
    int cnt = 0; long long prev = -1;
    for (int i = s; i < e; i++){
      int b = EB_B(ebuf[i]);
      if (b != prev){ cnt++; prev = b; }
    }
    ucnt[a] = cnt;
  }
}

// wave-per-bucket: emit verts + per-instance rank (rank_of, sequential in a-order)
__global__ void k_rank_emit(const int* __restrict__ bucketStart,
                            const unsigned long long* __restrict__ ebuf,
                            const int* __restrict__ vertBase, const float* __restrict__ pos,
                            const float* __restrict__ sdf, float* __restrict__ out,
                            int* __restrict__ rank_of){
  int lane = threadIdx.x & 63;
  int a = blockIdx.x*4 + (threadIdx.x >> 6);
  if (a >= kNV) return;
  int s = bucketStart[a], e = bucketStart[a+1];
  int k = e - s;
  if (k == 0) return;
  int base = vertBase[a];
  if (k <= 64){
    int val = (lane < k) ? EB_B(ebuf[s + lane]) : 0x7FFFFFFF;
    bool first = (lane < k);
    for (int j = 0; j < k; j++){
      int vj = __shfl(val, j);
      if (j < lane && vj == val) first = false;
    }
    unsigned long long m = __ballot(first);
    int rank = 0;
    for (int j = 0; j < k; j++){
      int vj = __shfl(val, j);
      if (((m >> j) & 1ULL) && vj < val) rank++;
    }
    if (lane < k){
      int r = base + rank;
      rank_of[s + lane] = r;
      if (first){
        int b = val;
        float sa = sdf[a], sb = sdf[b];
        float denom = sa - sb;               // s = [sa,-sb]; never 0 for a crossing edge
        float w0 = (-sb) / denom;
        float w1 = sa / denom;
        out[3LL*r + 0] = pos[3*a+0]*w0 + pos[3*b+0]*w1;
        out[3LL*r + 1] = pos[3*a+1]*w0 + pos[3*b+1]*w1;
        out[3LL*r + 2] = pos[3*a+2]*w0 + pos[3*b+2]*w1;
      }
    }
  } else if (lane == 0){
    // fallback: ebuf was sorted by k_rank_count's fallback
    float sa = sdf[a];
    float pax = pos[3*a], pay = pos[3*a+1], paz = pos[3*a+2];
    int r = base - 1;
    long long prev = -1;
    for (int i = s; i < e; i++){
      unsigned long long p = ebuf[i];
      int b = EB_B(p);
      if (b != prev){
        prev = b; r++;
        float sb = sdf[b];
        float denom = sa - sb;
        float w0 = (-sb) / denom, w1 = sa / denom;
        out[3LL*r + 0] = pax*w0 + pos[3*b+0]*w1;
        out[3LL*r + 1] = pay*w0 + pos[3*b+1]*w1;
        out[3LL*r + 2] = paz*w0 + pos[3*b+2]*w1;
      }
      rank_of[i] = r;
    }
  }
}

// faces + uv_idx: r = rank_of[posmap[dest[seq]]] — no dependent search
__global__ void k_faces(const int* __restrict__ tetinfo,
                        const unsigned long long* __restrict__ psum,
                        const int* __restrict__ vertBase,
                        const int* __restrict__ dest, const int* __restrict__ posmap,
                        const int* __restrict__ rank_of, float* __restrict__ out){
  int t = blockIdx.x*256 + threadIdx.x; if (t >= kNT) return;
  int pat = tetinfo[t];
  int nt_ = c_ntri[pat];
  if (nt_ == 0) return;
  unsigned long long tot = psum[kNT];
  int Nm1 = (int)(tot >> 44), Nm2 = (int)((tot >> 24) & 0xFFFFF);
  int Ne = vertBase[kNV];
  long long faces_off = 3LL*Ne;
  long long uvidx_off = faces_off + 3LL*((long long)Nm1 + 2LL*Nm2) + UVS_FLOATS;
  unsigned long long ps = psum[t];
  int m1v = (int)(ps >> 44), m2v = (int)((ps >> 24) & 0xFFFFF);
  int seq = (int)(ps & 0xFFFFFF);
  int er[6];
  int j = 0;
  #pragma unroll
  for (int e = 0; e < 6; e++){
    int i0 = c_edges[2*e], i1 = c_edges[2*e+1];
    if (((pat >> i0) & 1) != ((pat >> i1) & 1)){
      er[e] = rank_of[posmap[dest[seq + j]]];
      j++;
    } else er[e] = -1;
  }
  for (int k = 0; k < nt_; k++){
    long long row = (nt_ == 1) ? (long long)m1v : ((long long)Nm1 + 2LL*m2v + k);
    #pragma unroll
    for (int c = 0; c < 3; c++){
      int slot = c_tri[pat][3*k + c];
      out[faces_off + 3*row + c] = (float)er[slot];
    }
    out[uvidx_off + 3*row + 0] = (float)(4*t);
    out[uvidx_off + 3*row + 1] = (float)(4*t + k + 1);
    out[uvidx_off + 3*row + 2] = (float)(4*t + k + 2);
  }
}

__global__ void k_uvs(const unsigned long long* __restrict__ psum,
                      const int* __restrict__ vertBase, float* __restrict__ out){
  long long r = (long long)blockIdx.x*256 + threadIdx.x;
  if (r >= UVS_ROWS) return;
  unsigned long long tot = psum[kNT];
  int Nm1 = (int)(tot >> 44), Nm2 = (int)((tot >> 24) & 0xFFFFF);
  int Ne = vertBase[kNV];
  long long off = 3LL*Ne + 3LL*((long long)Nm1 + 2LL*Nm2);
  int cell = (int)(r >> 2), k = (int)(r & 3);
  int iy = cell / kNUV, ix = cell - iy*kNUV;
  const float delta = (1.0f - 1.0f/895.0f) / 894.0f;   // linspace(0, 1-1/N, N) step, f32
  const float pad = 0.9f / 895.0f;
  float x = (float)ix * delta, y = (float)iy * delta;
  float u = x + ((k == 1 || k == 2) ? pad : 0.0f);
  float v = y + ((k >= 2) ? pad : 0.0f);
  out[off + 2*r]     = u;
  out[off + 2*r + 1] = v;
}

// ---------------- host ----------------
static inline int divup(int a, int b){ return (a + b - 1) / b; }

extern "C" void kernel_launch(void* const* d_in, const int* in_sizes, int n_in,
                              void* d_out, int out_size, void* d_ws, size_t ws_size,
                              hipStream_t stream){
  const float* pos = (const float*)d_in[0];
  const float* sdf = (const float*)d_in[1];
  const int*   tet = (const int*)d_in[2];
  float* out = (float*)d_out;

  char* ws = (char*)d_ws;
  size_t off = 0;
  auto alloc = [&](size_t bytes) -> char* {
    char* p = ws + off; off += (bytes + 255) & ~(size_t)255; return p;
  };
  int* tetinfo                = (int*)alloc((size_t)kNT*4);
  unsigned long long* pk      = (unsigned long long*)alloc((size_t)kNT*8);
  unsigned long long* psum    = (unsigned long long*)alloc((size_t)(kNT+1)*8);
  int* blockHist              = (int*)alloc((size_t)NBIN*NH*4);
  int* bhScan                 = (int*)alloc((size_t)(NBIN*NH+1)*4);
  int* bucketStart            = (int*)alloc((size_t)(kNV+1)*4);
  int* ucnt                   = (int*)alloc((size_t)kNV*4);
  int* vertBase               = (int*)alloc((size_t)(kNV+1)*4);
  unsigned long long* ebin    = (unsigned long long*)alloc((size_t)CAP*8);
  unsigned long long* efin    = (unsigned long long*)alloc((size_t)CAP*8);
  int* dest                   = (int*)alloc((size_t)CAP*4);
  int* posmap                 = (int*)alloc((size_t)CAP*4);
  int* rank_of                = (int*)alloc((size_t)CAP*4);
  unsigned long long* part64  = (unsigned long long*)alloc(4096*8);
  int* partI                  = (int*)alloc(4096*4);
  if (off > ws_size){
    fprintf(stderr, "[dmtet] workspace too small: need %zu have %zu\n", off, ws_size);
    return;
  }

  k_classify<<<divup(kNT,256), 256, 0, stream>>>(tet, sdf, tetinfo, pk);
  run_scan<unsigned long long>(pk, psum, kNT, part64, stream);
  k_hist<<<NH, 256, 0, stream>>>(tet, tetinfo, blockHist);
  run_scan<int>(blockHist, bhScan, NBIN*NH, partI, stream);
  k_scatter<<<NH, 256, 0, stream>>>(tet, tetinfo, psum, bhScan, ebin, dest);
  k_fine<<<NBIN, 256, 0, stream>>>(bhScan, ebin, efin, bucketStart, posmap);
  k_rank_count<<<divup(kNV,4), 256, 0, stream>>>(bucketStart, efin, ucnt);
  run_scan<int>(ucnt, vertBase, kNV, partI, stream);
  k_rank_emit<<<divup(kNV,4), 256, 0, stream>>>(bucketStart, efin, vertBase, pos, sdf, out, rank_of);
  k_faces<<<divup(kNT,256), 256, 0, stream>>>(tetinfo, psum, vertBase, dest, posmap, rank_of, out);
  k_uvs<<<divup((int)UVS_ROWS,256), 256, 0, stream>>>(psum, vertBase, out);
}

// Round 5
// 332.840 us; speedup vs baseline: 2.0339x; 1.2099x over previous
//
#include <hip/hip_runtime.h>
#include <cstdio>
#include <cstdint>

typedef unsigned long long u64;

// ---------------- problem constants ----------------
static const int kNV = 200000;
static const int kNT = 800000;
static const int kNUV = 895;                       // ceil(sqrt((2*NT+1)//2))
#define UVS_ROWS   3204100LL                       // kNUV*kNUV*4
#define UVS_FLOATS 6408200LL                       // UVS_ROWS*2
#define CAP 3300000                                // max crossing-edge instances (<= 4*NT = 3.2M)

// counting-sort geometry
#define NH 392                                     // classify/hist/scatter blocks
#define TILE_T 2048                                // tets per block (NH*TILE_T >= kNT)
#define BINW 512                                   // a-values per coarse bin
#define NBIN 391                                   // ceil(200000/512)

__device__ const int c_tri[16][6] = {
    {-1,-1,-1,-1,-1,-1},{1,0,2,-1,-1,-1},{4,0,3,-1,-1,-1},{1,4,2,1,3,4},
    {3,1,5,-1,-1,-1},{2,3,0,2,5,3},{1,4,0,1,5,4},{4,2,5,-1,-1,-1},
    {4,5,2,-1,-1,-1},{4,1,0,4,5,1},{3,2,0,3,5,2},{1,3,5,-1,-1,-1},
    {4,1,2,4,3,1},{3,0,4,-1,-1,-1},{2,0,1,-1,-1,-1},{-1,-1,-1,-1,-1,-1}};
__device__ const int c_ntri[16]   = {0,1,1,2,1,2,2,1,1,2,2,1,2,1,1,0};
__device__ const int c_ncross[16] = {0,3,3,4,3,4,4,3,3,4,4,3,4,3,3,0};
__device__ const int c_edges[12] = {0,1,0,2,0,3,1,2,1,3,2,3};

// psum packing: m1 <<44 | m2 <<24 | ncross (m1,m2 totals < 2^20, ncross total < 2^24)
#define PK(m1,m2,nc) (((u64)(m1) << 44) | ((u64)(m2) << 24) | (u64)(nc))
// ebin packing: a <<40 | b <<22 | seq (a,b < 2^18, seq < 2^22)

// ---------------- generic exclusive scan (templated, 3 kernels) ----------------
#define SCAN_B 256
#define SCAN_I 8
#define SCAN_TILE (SCAN_B*SCAN_I)

template<typename T>
__global__ void k_scan_partial(const T* __restrict__ in, T* __restrict__ partials, int n){
  __shared__ T sm[SCAN_B];
  int b = blockIdx.x;
  long long base = (long long)b*SCAN_TILE;
  T sum = 0;
  for (int i = threadIdx.x; i < SCAN_TILE; i += SCAN_B){
    long long idx = base + i;
    if (idx < n) sum += in[idx];
  }
  sm[threadIdx.x] = sum; __syncthreads();
  for (int s = SCAN_B/2; s > 0; s >>= 1){
    if ((int)threadIdx.x < s) sm[threadIdx.x] += sm[threadIdx.x + s];
    __syncthreads();
  }
  if (threadIdx.x == 0) partials[b] = sm[0];
}

template<typename T>
__global__ void k_scan_blocksums(T* __restrict__ partials, int nb, T* __restrict__ total_out){
  __shared__ T sm[SCAN_B];
  T carry = 0;
  for (int base = 0; base < nb; base += SCAN_B){
    int i = base + (int)threadIdx.x;
    T v = (i < nb) ? partials[i] : (T)0;
    sm[threadIdx.x] = v; __syncthreads();
    for (int off = 1; off < SCAN_B; off <<= 1){
      T t = ((int)threadIdx.x >= off) ? sm[threadIdx.x - off] : (T)0;
      __syncthreads();
      sm[threadIdx.x] += t;
      __syncthreads();
    }
    if (i < nb) partials[i] = carry + sm[threadIdx.x] - v;  // exclusive
    T tilesum = sm[SCAN_B-1];
    __syncthreads();
    carry += tilesum;
  }
  if (threadIdx.x == 0 && total_out) *total_out = carry;
}

template<typename T>
__global__ void k_scan_apply(const T* __restrict__ in, T* __restrict__ out,
                             const T* __restrict__ partials, int n){
  __shared__ T sm[SCAN_B];
  int b = blockIdx.x;
  long long base = (long long)b*SCAN_TILE + (long long)threadIdx.x*SCAN_I;
  T v[SCAN_I]; T s = 0;
  #pragma unroll
  for (int k = 0; k < SCAN_I; k++){ long long idx = base + k; v[k] = (idx < n) ? in[idx] : (T)0; s += v[k]; }
  sm[threadIdx.x] = s; __syncthreads();
  for (int off = 1; off < SCAN_B; off <<= 1){
    T t = ((int)threadIdx.x >= off) ? sm[threadIdx.x - off] : (T)0;
    __syncthreads();
    sm[threadIdx.x] += t;
    __syncthreads();
  }
  T excl = sm[threadIdx.x] - s + partials[b];
  #pragma unroll
  for (int k = 0; k < SCAN_I; k++){ long long idx = base + k; if (idx < n) out[idx] = excl; excl += v[k]; }
}

template<typename T>
static void run_scan(const T* in, T* out, int n, T* partials, hipStream_t s){
  int nb = (n + SCAN_TILE - 1) / SCAN_TILE;
  k_scan_partial<T><<<nb, SCAN_B, 0, s>>>(in, partials, n);
  k_scan_blocksums<T><<<1, SCAN_B, 0, s>>>(partials, nb, out + n);  // total -> out[n]
  k_scan_apply<T><<<nb, SCAN_B, 0, s>>>(in, out, partials, n);
}

// ---------------- pipeline kernels ----------------

// fused: per-tet occupancy pattern + (m1,m2,ncross) pack + coarse-bin histogram
__global__ void k_classify_hist(const int* __restrict__ tet, const float* __restrict__ sdf,
                                int* __restrict__ tetinfo, u64* __restrict__ pk,
                                int* __restrict__ blockHist){
  __shared__ int h[NBIN];
  int blk = blockIdx.x;
  for (int j = threadIdx.x; j < NBIN; j += 256) h[j] = 0;
  __syncthreads();
  int t0 = blk*TILE_T;
  for (int k = 0; k < TILE_T/256; k++){
    int t = t0 + k*256 + threadIdx.x;
    if (t < kNT){
      int4 v4 = ((const int4*)tet)[t];
      int pat = ((sdf[v4.x] > 0.0f) ? 1 : 0) | ((sdf[v4.y] > 0.0f) ? 2 : 0)
              | ((sdf[v4.z] > 0.0f) ? 4 : 0) | ((sdf[v4.w] > 0.0f) ? 8 : 0);
      tetinfo[t] = pat;
      int nt_ = c_ntri[pat];
      pk[t] = PK(nt_ == 1, nt_ == 2, c_ncross[pat]);
      if (pat != 0 && pat != 15){
        int vv[4] = {v4.x, v4.y, v4.z, v4.w};
        #pragma unroll
        for (int e = 0; e < 6; e++){
          int i0 = c_edges[2*e], i1 = c_edges[2*e+1];
          if (((pat >> i0) & 1) != ((pat >> i1) & 1)){
            int a = vv[i0], b = vv[i1]; if (a > b){ int tm = a; a = b; b = tm; }
            atomicAdd(&h[a >> 9], 1);
          }
        }
      }
    }
  }
  __syncthreads();
  for (int j = threadIdx.x; j < NBIN; j += 256) blockHist[j*NH + blk] = h[j];  // bin-major
}

// scatter instances to bin-grouped buffer via LDS cursors; record dest[seq]
__global__ void k_scatter(const int* __restrict__ tet, const int* __restrict__ tetinfo,
                          const u64* __restrict__ psum, const int* __restrict__ bhScan,
                          u64* __restrict__ ebin, int* __restrict__ dest){
  __shared__ int c[NBIN];
  int blk = blockIdx.x;
  for (int j = threadIdx.x; j < NBIN; j += 256) c[j] = bhScan[j*NH + blk];
  __syncthreads();
  int t0 = blk*TILE_T;
  for (int k = 0; k < TILE_T/256; k++){
    int t = t0 + k*256 + threadIdx.x;
    if (t < kNT){
      int pat = tetinfo[t];
      if (pat != 0 && pat != 15){
        int4 v4 = ((const int4*)tet)[t];
        int vv[4] = {v4.x, v4.y, v4.z, v4.w};
        int seq = (int)(psum[t] & 0xFFFFFF);
        #pragma unroll
        for (int e = 0; e < 6; e++){
          int i0 = c_edges[2*e], i1 = c_edges[2*e+1];
          if (((pat >> i0) & 1) != ((pat >> i1) & 1)){
            int a = vv[i0], b = vv[i1]; if (a > b){ int tm = a; a = b; b = tm; }
            int pos = atomicAdd(&c[a >> 9], 1);
            ebin[pos] = ((u64)(unsigned)a << 40) | ((u64)(unsigned)b << 22) | (unsigned)seq;
            dest[seq] = pos;
            seq++;
          }
        }
      }
    }
  }
}

// per coarse bin: exact-a regroup + posmap (binpos -> finalpos). efin is globally a-sorted.
__global__ void k_fine(const int* __restrict__ bhScan, const u64* __restrict__ ebin,
                       u64* __restrict__ efin, int* __restrict__ posmap){
  __shared__ int h[BINW];
  __shared__ int ss[256];
  int bin = blockIdx.x;
  int binStart = bhScan[bin*NH];
  int binEnd   = bhScan[(bin+1)*NH];     // scan stores total at [n] for the last bin
  int a0 = bin << 9;
  for (int j = threadIdx.x; j < BINW; j += 256) h[j] = 0;
  __syncthreads();
  for (int i = binStart + threadIdx.x; i < binEnd; i += 256){
    int a = (int)(ebin[i] >> 40);
    atomicAdd(&h[a - a0], 1);
  }
  __syncthreads();
  // exclusive scan of h[512] with 256 threads (2 elements each)
  int tid = threadIdx.x;
  int s0 = h[2*tid], s1 = h[2*tid+1];
  int pair = s0 + s1;
  ss[tid] = pair; __syncthreads();
  for (int off = 1; off < 256; off <<= 1){
    int v = (tid >= off) ? ss[tid - off] : 0;
    __syncthreads();
    ss[tid] += v;
    __syncthreads();
  }
  int excl = ss[tid] - pair;
  h[2*tid] = excl; h[2*tid+1] = excl + s0;
  __syncthreads();
  // regroup: h serves as per-a cursors (exclusive offsets)
  for (int i = binStart + tid; i < binEnd; i += 256){
    u64 p = ebin[i];
    int j = (int)(p >> 40) - a0;
    int pos = binStart + atomicAdd(&h[j], 1);
    efin[pos] = p;
    posmap[i] = pos;
  }
}

// item-parallel first/rank/off over a-sorted efin, using an LDS window with 64-item halos.
#define FB 256
#define FH 64
#define FW (FB + 2*FH)   // 384
__global__ void k_flags(const u64* __restrict__ efin, const int* __restrict__ totp,
                        int* __restrict__ firstI, unsigned* __restrict__ meta){
  __shared__ u64 ld[FW];
  __shared__ unsigned char fl[FW];
  int total = *totp;
  int tid = threadIdx.x;
  long long base = (long long)blockIdx.x * FB;
  for (int x = tid; x < FW; x += FB){
    long long gi = base - FH + x;
    ld[x] = (gi >= 0 && gi < total) ? (efin[gi] >> 22) : ~0ULL;   // key36 = a<<18 | b
  }
  __syncthreads();
  // phase 1: first-occurrence flags for window + halos (left scan within bucket)
  for (int x = tid; x < FW; x += FB){
    u64 key = ld[x];
    u64 buck = key >> 18;
    unsigned char f = 1;
    for (int y = x-1; y >= 0; y--){
      u64 ky = ld[y];
      if ((ky >> 18) != buck) break;
      if (ky == key){ f = 0; break; }
    }
    fl[x] = f;
  }
  __syncthreads();
  // phase 2: per window item: bucket range, rank = #distinct smaller b
  long long gi = base + tid;
  if (gi < total){
    int x = FH + tid;
    u64 key = ld[x];
    u64 buck = key >> 18;
    int sx = x; while (sx > 0 && (ld[sx-1] >> 18) == buck) sx--;
    int ex = x+1; while (ex < FW && (ld[ex] >> 18) == buck) ex++;
    int first, rank, off;
    if (sx > 0 && ex < FW){
      first = fl[x];
      int rk = 0;
      for (int y = sx; y < ex; y++) if (fl[y] && ld[y] < key) rk++;
      rank = rk; off = x - sx;
    } else {
      // slow path: bucket spans past the LDS window (bucket > 64; statistically never)
      u64 keyg = efin[gi] >> 22;
      u64 buckg = keyg >> 18;
      long long s = gi; while (s > 0 && (efin[s-1] >> 40) == buckg) s--;
      long long e = gi + 1; while (e < total && (efin[e] >> 40) == buckg) e++;
      int f = 1;
      for (long long j = s; j < gi; j++) if ((efin[j] >> 22) == keyg){ f = 0; break; }
      int rk = 0;
      for (long long j = s; j < e; j++){
        u64 kj = efin[j] >> 22;
        if (kj < keyg){
          bool fj = true;
          for (long long l = s; l < j; l++) if ((efin[l] >> 22) == kj){ fj = false; break; }
          if (fj) rk++;
        }
      }
      first = f; rank = rk; off = (int)(gi - s);
    }
    firstI[gi] = first;
    meta[gi] = (unsigned)rank | ((unsigned)off << 12) | ((unsigned)first << 24);
  } else if (gi < CAP){
    firstI[gi] = 0;      // zero-fill tail so the CAP-length scan is exact
    meta[gi] = 0;
  }
}

// item-parallel: vertex index r = fscan[bucketStart] + rank; emit verts (firsts) + rank_of
__global__ void k_emit(const u64* __restrict__ efin, const int* __restrict__ totp,
                       const int* __restrict__ fscan, const unsigned* __restrict__ meta,
                       const float* __restrict__ pos, const float* __restrict__ sdf,
                       float* __restrict__ out, int* __restrict__ rank_of){
  int total = *totp;
  int i = blockIdx.x*256 + threadIdx.x;
  if (i >= total) return;
  u64 p = efin[i];
  unsigned m = meta[i];
  int rank = m & 0xFFF, off = (m >> 12) & 0xFFF, first = (m >> 24) & 1;
  int r = fscan[i - off] + rank;
  rank_of[i] = r;
  if (first){
    int a = (int)(p >> 40);
    int b = (int)((p >> 22) & 0x3FFFF);
    float sa = sdf[a], sb = sdf[b];
    float denom = sa - sb;               // s = [sa,-sb]; never 0 for a crossing edge
    float w0 = (-sb) / denom;
    float w1 = sa / denom;
    out[3LL*r + 0] = pos[3*a+0]*w0 + pos[3*b+0]*w1;
    out[3LL*r + 1] = pos[3*a+1]*w0 + pos[3*b+1]*w1;
    out[3LL*r + 2] = pos[3*a+2]*w0 + pos[3*b+2]*w1;
  }
}

// faces + uv_idx: r = rank_of[posmap[dest[seq]]]
__global__ void k_faces(const int* __restrict__ tetinfo, const u64* __restrict__ psum,
                        const int* __restrict__ fscan,
                        const int* __restrict__ dest, const int* __restrict__ posmap,
                        const int* __restrict__ rank_of, float* __restrict__ out){
  int t = blockIdx.x*256 + threadIdx.x; if (t >= kNT) return;
  int pat = tetinfo[t];
  int nt_ = c_ntri[pat];
  if (nt_ == 0) return;
  u64 tot = psum[kNT];
  int Nm1 = (int)(tot >> 44), Nm2 = (int)((tot >> 24) & 0xFFFFF);
  int Ne = fscan[CAP];
  long long faces_off = 3LL*Ne;
  long long uvidx_off = faces_off + 3LL*((long long)Nm1 + 2LL*Nm2) + UVS_FLOATS;
  u64 ps = psum[t];
  int m1v = (int)(ps >> 44), m2v = (int)((ps >> 24) & 0xFFFFF);
  int seq = (int)(ps & 0xFFFFFF);
  int er[6];
  int j = 0;
  #pragma unroll
  for (int e = 0; e < 6; e++){
    int i0 = c_edges[2*e], i1 = c_edges[2*e+1];
    if (((pat >> i0) & 1) != ((pat >> i1) & 1)){
      er[e] = rank_of[posmap[dest[seq + j]]];
      j++;
    } else er[e] = -1;
  }
  for (int k = 0; k < nt_; k++){
    long long row = (nt_ == 1) ? (long long)m1v : ((long long)Nm1 + 2LL*m2v + k);
    #pragma unroll
    for (int c = 0; c < 3; c++){
      int slot = c_tri[pat][3*k + c];
      out[faces_off + 3*row + c] = (float)er[slot];
    }
    out[uvidx_off + 3*row + 0] = (float)(4*t);
    out[uvidx_off + 3*row + 1] = (float)(4*t + k + 1);
    out[uvidx_off + 3*row + 2] = (float)(4*t + k + 2);
  }
}

__global__ void k_uvs(const u64* __restrict__ psum, const int* __restrict__ fscan,
                      float* __restrict__ out){
  long long r = (long long)blockIdx.x*256 + threadIdx.x;
  if (r >= UVS_ROWS) return;
  u64 tot = psum[kNT];
  int Nm1 = (int)(tot >> 44), Nm2 = (int)((tot >> 24) & 0xFFFFF);
  int Ne = fscan[CAP];
  long long off = 3LL*Ne + 3LL*((long long)Nm1 + 2LL*Nm2);
  int cell = (int)(r >> 2), k = (int)(r & 3);
  int iy = cell / kNUV, ix = cell - iy*kNUV;
  const float delta = (1.0f - 1.0f/895.0f) / 894.0f;   // linspace(0, 1-1/N, N) step, f32
  const float pad = 0.9f / 895.0f;
  float x = (float)ix * delta, y = (float)iy * delta;
  float u = x + ((k == 1 || k == 2) ? pad : 0.0f);
  float v = y + ((k >= 2) ? pad : 0.0f);
  out[off + 2*r]     = u;
  out[off + 2*r + 1] = v;
}

// ---------------- host ----------------
static inline int divup(int a, int b){ return (a + b - 1) / b; }

extern "C" void kernel_launch(void* const* d_in, const int* in_sizes, int n_in,
                              void* d_out, int out_size, void* d_ws, size_t ws_size,
                              hipStream_t stream){
  const float* pos = (const float*)d_in[0];
  const float* sdf = (const float*)d_in[1];
  const int*   tet = (const int*)d_in[2];
  float* out = (float*)d_out;

  char* ws = (char*)d_ws;
  size_t off = 0;
  auto alloc = [&](size_t bytes) -> char* {
    char* p = ws + off; off += (bytes + 255) & ~(size_t)255; return p;
  };
  int* tetinfo     = (int*)alloc((size_t)kNT*4);
  u64* pk          = (u64*)alloc((size_t)kNT*8);
  u64* psum        = (u64*)alloc((size_t)(kNT+1)*8);
  int* blockHist   = (int*)alloc((size_t)NBIN*NH*4);
  int* bhScan      = (int*)alloc((size_t)(NBIN*NH+1)*4);
  u64* ebin        = (u64*)alloc((size_t)CAP*8);
  u64* efin        = (u64*)alloc((size_t)CAP*8);
  int* dest        = (int*)alloc((size_t)CAP*4);
  int* posmap      = (int*)alloc((size_t)CAP*4);
  int* rank_of     = (int*)alloc((size_t)CAP*4);
  int* fscan       = (int*)alloc((size_t)(CAP+1)*4);
  u64* part64      = (u64*)alloc(4096*8);
  int* partI       = (int*)alloc(4096*4);
  // ebin is dead after k_fine: alias the flags outputs onto it
  int* firstI      = (int*)ebin;
  unsigned* meta   = (unsigned*)((char*)ebin + (size_t)CAP*4);
  if (off > ws_size){
    fprintf(stderr, "[dmtet] workspace too small: need %zu have %zu\n", off, ws_size);
    return;
  }

  k_classify_hist<<<NH, 256, 0, stream>>>(tet, sdf, tetinfo, pk, blockHist);
  run_scan<u64>(pk, psum, kNT, part64, stream);
  run_scan<int>(blockHist, bhScan, NBIN*NH, partI, stream);
  k_scatter<<<NH, 256, 0, stream>>>(tet, tetinfo, psum, bhScan, ebin, dest);
  k_fine<<<NBIN, 256, 0, stream>>>(bhScan, ebin, efin, posmap);
  k_flags<<<divup(CAP,FB), FB, 0, stream>>>(efin, bhScan + NBIN*NH, firstI, meta);
  run_scan<int>(firstI, fscan, CAP, partI, stream);
  k_emit<<<divup(CAP,256), 256, 0, stream>>>(efin, bhScan + NBIN*NH, fscan, meta,
                                             pos, sdf, out, rank_of);
  k_faces<<<divup(kNT,256), 256, 0, stream>>>(tetinfo, psum, fscan, dest, posmap, rank_of, out);
  k_uvs<<<divup((int)UVS_ROWS,256), 256, 0, stream>>>(psum, fscan, out);
}

// Round 6
// 281.284 us; speedup vs baseline: 2.4067x; 1.1833x over previous
//
#include <hip/hip_runtime.h>
#include <cstdio>
#include <cstdint>

typedef unsigned long long u64;

// ---------------- problem constants ----------------
static const int kNV = 200000;
static const int kNT = 800000;
static const int kNUV = 895;                       // ceil(sqrt((2*NT+1)//2))
#define UVS_ROWS   3204100LL                       // kNUV*kNUV*4
#define UVS_FLOATS 6408200LL                       // UVS_ROWS*2
#define CAP 3300000                                // max crossing-edge instances (<= 4*NT = 3.2M)

// counting-sort geometry
#define NH 392                                     // classify/hist/scatter blocks
#define TILE_T 2048                                // tets per block (NH*TILE_T >= kNT)
#define BINW 256                                   // a-values per coarse bin
#define NBIN 782                                   // ceil(200000/256)
#define SUBSH 15                                   // sub-bucket = (a, b>>SUBSH)
#define FINEB 2048                                 // BINW * (1<<(18-SUBSH)) fine cursors

__device__ const int c_tri[16][6] = {
    {-1,-1,-1,-1,-1,-1},{1,0,2,-1,-1,-1},{4,0,3,-1,-1,-1},{1,4,2,1,3,4},
    {3,1,5,-1,-1,-1},{2,3,0,2,5,3},{1,4,0,1,5,4},{4,2,5,-1,-1,-1},
    {4,5,2,-1,-1,-1},{4,1,0,4,5,1},{3,2,0,3,5,2},{1,3,5,-1,-1,-1},
    {4,1,2,4,3,1},{3,0,4,-1,-1,-1},{2,0,1,-1,-1,-1},{-1,-1,-1,-1,-1,-1}};
__device__ const int c_ntri[16]   = {0,1,1,2,1,2,2,1,1,2,2,1,2,1,1,0};
__device__ const int c_ncross[16] = {0,3,3,4,3,4,4,3,3,4,4,3,4,3,3,0};
__device__ const int c_edges[12] = {0,1,0,2,0,3,1,2,1,3,2,3};

// psum packing: m1 <<44 | m2 <<24 | ncross (m1,m2 totals < 2^20, ncross total < 2^24)
#define PK(m1,m2,nc) (((u64)(m1) << 44) | ((u64)(m2) << 24) | (u64)(nc))
// ebin packing: a <<40 | b <<22 | seq (a,b < 2^18, seq < 2^22); key36 = p>>22; group = key36>>SUBSH

// ---------------- generic exclusive scan (templated, 3 kernels) ----------------
#define SCAN_B 256
#define SCAN_I 8
#define SCAN_TILE (SCAN_B*SCAN_I)

template<typename T>
__global__ void k_scan_partial(const T* __restrict__ in, T* __restrict__ partials, int n){
  __shared__ T sm[SCAN_B];
  int b = blockIdx.x;
  long long base = (long long)b*SCAN_TILE;
  T sum = 0;
  for (int i = threadIdx.x; i < SCAN_TILE; i += SCAN_B){
    long long idx = base + i;
    if (idx < n) sum += in[idx];
  }
  sm[threadIdx.x] = sum; __syncthreads();
  for (int s = SCAN_B/2; s > 0; s >>= 1){
    if ((int)threadIdx.x < s) sm[threadIdx.x] += sm[threadIdx.x + s];
    __syncthreads();
  }
  if (threadIdx.x == 0) partials[b] = sm[0];
}

template<typename T>
__global__ void k_scan_blocksums(T* __restrict__ partials, int nb, T* __restrict__ total_out){
  __shared__ T sm[SCAN_B];
  T carry = 0;
  for (int base = 0; base < nb; base += SCAN_B){
    int i = base + (int)threadIdx.x;
    T v = (i < nb) ? partials[i] : (T)0;
    sm[threadIdx.x] = v; __syncthreads();
    for (int off = 1; off < SCAN_B; off <<= 1){
      T t = ((int)threadIdx.x >= off) ? sm[threadIdx.x - off] : (T)0;
      __syncthreads();
      sm[threadIdx.x] += t;
      __syncthreads();
    }
    if (i < nb) partials[i] = carry + sm[threadIdx.x] - v;  // exclusive
    T tilesum = sm[SCAN_B-1];
    __syncthreads();
    carry += tilesum;
  }
  if (threadIdx.x == 0 && total_out) *total_out = carry;
}

template<typename T>
__global__ void k_scan_apply(const T* __restrict__ in, T* __restrict__ out,
                             const T* __restrict__ partials, int n){
  __shared__ T sm[SCAN_B];
  int b = blockIdx.x;
  long long base = (long long)b*SCAN_TILE + (long long)threadIdx.x*SCAN_I;
  T v[SCAN_I]; T s = 0;
  #pragma unroll
  for (int k = 0; k < SCAN_I; k++){ long long idx = base + k; v[k] = (idx < n) ? in[idx] : (T)0; s += v[k]; }
  sm[threadIdx.x] = s; __syncthreads();
  for (int off = 1; off < SCAN_B; off <<= 1){
    T t = ((int)threadIdx.x >= off) ? sm[threadIdx.x - off] : (T)0;
    __syncthreads();
    sm[threadIdx.x] += t;
    __syncthreads();
  }
  T excl = sm[threadIdx.x] - s + partials[b];
  #pragma unroll
  for (int k = 0; k < SCAN_I; k++){ long long idx = base + k; if (idx < n) out[idx] = excl; excl += v[k]; }
}

template<typename T>
static void run_scan(const T* in, T* out, int n, T* partials, hipStream_t s){
  int nb = (n + SCAN_TILE - 1) / SCAN_TILE;
  k_scan_partial<T><<<nb, SCAN_B, 0, s>>>(in, partials, n);
  k_scan_blocksums<T><<<1, SCAN_B, 0, s>>>(partials, nb, out + n);  // total -> out[n]
  k_scan_apply<T><<<nb, SCAN_B, 0, s>>>(in, out, partials, n);
}

// ---------------- pipeline kernels ----------------

// fused: per-tet occupancy pattern + (m1,m2,ncross) pack + coarse-bin histogram
__global__ void k_classify_hist(const int* __restrict__ tet, const float* __restrict__ sdf,
                                int* __restrict__ tetinfo, u64* __restrict__ pk,
                                int* __restrict__ blockHist){
  __shared__ int h[NBIN];
  int blk = blockIdx.x;
  for (int j = threadIdx.x; j < NBIN; j += 256) h[j] = 0;
  __syncthreads();
  int t0 = blk*TILE_T;
  for (int k = 0; k < TILE_T/256; k++){
    int t = t0 + k*256 + threadIdx.x;
    if (t < kNT){
      int4 v4 = ((const int4*)tet)[t];
      int pat = ((sdf[v4.x] > 0.0f) ? 1 : 0) | ((sdf[v4.y] > 0.0f) ? 2 : 0)
              | ((sdf[v4.z] > 0.0f) ? 4 : 0) | ((sdf[v4.w] > 0.0f) ? 8 : 0);
      tetinfo[t] = pat;
      int nt_ = c_ntri[pat];
      pk[t] = PK(nt_ == 1, nt_ == 2, c_ncross[pat]);
      if (pat != 0 && pat != 15){
        int vv[4] = {v4.x, v4.y, v4.z, v4.w};
        #pragma unroll
        for (int e = 0; e < 6; e++){
          int i0 = c_edges[2*e], i1 = c_edges[2*e+1];
          if (((pat >> i0) & 1) != ((pat >> i1) & 1)){
            int a = vv[i0], b = vv[i1]; if (a > b){ int tm = a; a = b; b = tm; }
            atomicAdd(&h[a >> 8], 1);
          }
        }
      }
    }
  }
  __syncthreads();
  for (int j = threadIdx.x; j < NBIN; j += 256) blockHist[j*NH + blk] = h[j];  // bin-major
}

// scatter instances to bin-grouped buffer via LDS cursors; record dest[seq] (sequential)
__global__ void k_scatter(const int* __restrict__ tet, const int* __restrict__ tetinfo,
                          const u64* __restrict__ psum, const int* __restrict__ bhScan,
                          u64* __restrict__ ebin, int* __restrict__ dest){
  __shared__ int c[NBIN];
  int blk = blockIdx.x;
  for (int j = threadIdx.x; j < NBIN; j += 256) c[j] = bhScan[j*NH + blk];
  __syncthreads();
  int t0 = blk*TILE_T;
  for (int k = 0; k < TILE_T/256; k++){
    int t = t0 + k*256 + threadIdx.x;
    if (t < kNT){
      int pat = tetinfo[t];
      if (pat != 0 && pat != 15){
        int4 v4 = ((const int4*)tet)[t];
        int vv[4] = {v4.x, v4.y, v4.z, v4.w};
        int seq = (int)(psum[t] & 0xFFFFFF);
        #pragma unroll
        for (int e = 0; e < 6; e++){
          int i0 = c_edges[2*e], i1 = c_edges[2*e+1];
          if (((pat >> i0) & 1) != ((pat >> i1) & 1)){
            int a = vv[i0], b = vv[i1]; if (a > b){ int tm = a; a = b; b = tm; }
            int pos = atomicAdd(&c[a >> 8], 1);
            ebin[pos] = ((u64)(unsigned)a << 40) | ((u64)(unsigned)b << 22) | (unsigned)seq;
            dest[seq] = pos;
            seq++;
          }
        }
      }
    }
  }
}

// per coarse bin: regroup by fine key (a&255)<<3 | b>>15 + posmap (binpos -> finalpos).
// efin ends up globally sorted by (a, b>>15) -> groups for k_flags are tiny (k ~ 1.5).
__global__ void k_fine(const int* __restrict__ bhScan, const u64* __restrict__ ebin,
                       u64* __restrict__ efin, int* __restrict__ posmap){
  __shared__ int h[FINEB];
  __shared__ int ss[256];
  int bin = blockIdx.x;
  int binStart = bhScan[bin*NH];
  int binEnd   = bhScan[(bin+1)*NH];     // scan stores total at [n] for the last bin
  int a0 = bin << 8;
  for (int j = threadIdx.x; j < FINEB; j += 256) h[j] = 0;
  __syncthreads();
  for (int i = binStart + threadIdx.x; i < binEnd; i += 256){
    u64 p = ebin[i];
    int a = (int)(p >> 40);
    int bh = (int)((p >> 22) & 0x3FFFF) >> SUBSH;
    atomicAdd(&h[((a - a0) << 3) | bh], 1);
  }
  __syncthreads();
  // exclusive scan of h[2048] with 256 threads (8 elements each)
  int tid = threadIdx.x;
  int base8 = tid*8;
  int loc[8]; int s = 0;
  #pragma unroll
  for (int q = 0; q < 8; q++){ loc[q] = h[base8+q]; s += loc[q]; }
  ss[tid] = s; __syncthreads();
  for (int off = 1; off < 256; off <<= 1){
    int v = (tid >= off) ? ss[tid - off] : 0;
    __syncthreads();
    ss[tid] += v;
    __syncthreads();
  }
  int excl = ss[tid] - s;
  #pragma unroll
  for (int q = 0; q < 8; q++){ h[base8+q] = excl; excl += loc[q]; }
  __syncthreads();
  // regroup: h serves as per-fine-key cursors (exclusive offsets)
  for (int i = binStart + tid; i < binEnd; i += 256){
    u64 p = ebin[i];
    int a = (int)(p >> 40);
    int bh = (int)((p >> 22) & 0x3FFFF) >> SUBSH;
    int pos = binStart + atomicAdd(&h[((a - a0) << 3) | bh], 1);
    efin[pos] = p;
    posmap[i] = pos;
  }
}

// item-parallel first/rank/off over (a,b>>15)-sorted efin, LDS window with halos.
#define FB 256
#define FH 32
#define FW (FB + 2*FH)   // 320
__global__ void k_flags(const u64* __restrict__ efin, const int* __restrict__ totp,
                        int* __restrict__ firstI, unsigned* __restrict__ meta){
  __shared__ u64 ld[FW];
  __shared__ unsigned char fl[FW];
  int total = *totp;
  int tid = threadIdx.x;
  long long base = (long long)blockIdx.x * FB;
  long long gi = base + tid;
  if (base >= total){                       // pure tail block: zero-fill, no window
    if (gi < CAP){ firstI[gi] = 0; meta[gi] = 0; }
    return;
  }
  for (int x = tid; x < FW; x += FB){
    long long g = base - FH + x;
    ld[x] = (g >= 0 && g < total) ? (efin[g] >> 22) : ~0ULL;   // key36 = a<<18 | b
  }
  __syncthreads();
  // phase 1: first-occurrence flags for window + halos (left scan within group)
  for (int x = tid; x < FW; x += FB){
    u64 key = ld[x];
    u64 grp = key >> SUBSH;
    unsigned char f = 1;
    for (int y = x-1; y >= 0; y--){
      u64 ky = ld[y];
      if ((ky >> SUBSH) != grp) break;
      if (ky == key){ f = 0; break; }
    }
    fl[x] = f;
  }
  __syncthreads();
  // phase 2: per item: group range, rank = #distinct smaller keys in group
  if (gi < total){
    int x = FH + tid;
    u64 key = ld[x];
    u64 grp = key >> SUBSH;
    int sx = x; while (sx > 0 && (ld[sx-1] >> SUBSH) == grp) sx--;
    int ex = x+1; while (ex < FW && (ld[ex] >> SUBSH) == grp) ex++;
    int first, rank, off;
    if (sx > 0 && ex < FW){
      first = fl[x];
      int rk = 0;
      for (int y = sx; y < ex; y++) if (fl[y] && ld[y] < key) rk++;
      rank = rk; off = x - sx;
    } else {
      // slow path: group spans past the LDS window (group > 32 items; statistically never)
      u64 keyg = efin[gi] >> 22;
      u64 grpg = keyg >> SUBSH;
      long long s = gi; while (s > 0 && ((efin[s-1] >> 22) >> SUBSH) == grpg) s--;
      long long e = gi + 1; while (e < total && ((efin[e] >> 22) >> SUBSH) == grpg) e++;
      int f = 1;
      for (long long j = s; j < gi; j++) if ((efin[j] >> 22) == keyg){ f = 0; break; }
      int rk = 0;
      for (long long j = s; j < e; j++){
        u64 kj = efin[j] >> 22;
        if (kj < keyg){
          bool fj = true;
          for (long long l = s; l < j; l++) if ((efin[l] >> 22) == kj){ fj = false; break; }
          if (fj) rk++;
        }
      }
      first = f; rank = rk; off = (int)(gi - s);
    }
    firstI[gi] = first;
    meta[gi] = (unsigned)rank | ((unsigned)off << 12) | ((unsigned)first << 24);
  } else if (gi < CAP){
    firstI[gi] = 0;      // straddling block's tail: zero-fill for exact CAP-length scan
    meta[gi] = 0;
  }
}

// item-parallel: vertex index r = fscan[group_start] + rank; emit verts (firsts) + rank_of
__global__ void k_emit(const u64* __restrict__ efin, const int* __restrict__ totp,
                       const int* __restrict__ fscan, const unsigned* __restrict__ meta,
                       const float* __restrict__ pos, const float* __restrict__ sdf,
                       float* __restrict__ out, int* __restrict__ rank_of){
  int total = *totp;
  int i = blockIdx.x*256 + threadIdx.x;
  if (i >= total) return;
  u64 p = efin[i];
  unsigned m = meta[i];
  int rank = m & 0xFFF, off = (m >> 12) & 0xFFF, first = (m >> 24) & 1;
  int r = fscan[i - off] + rank;
  rank_of[i] = r;
  if (first){
    int a = (int)(p >> 40);
    int b = (int)((p >> 22) & 0x3FFFF);
    float sa = sdf[a], sb = sdf[b];
    float denom = sa - sb;               // s = [sa,-sb]; never 0 for a crossing edge
    float w0 = (-sb) / denom;
    float w1 = sa / denom;
    out[3LL*r + 0] = pos[3*a+0]*w0 + pos[3*b+0]*w1;
    out[3LL*r + 1] = pos[3*a+1]*w0 + pos[3*b+1]*w1;
    out[3LL*r + 2] = pos[3*a+2]*w0 + pos[3*b+2]*w1;
  }
}

// faces + uv_idx: r = rank_of[posmap[dest[seq]]]
__global__ void k_faces(const int* __restrict__ tetinfo, const u64* __restrict__ psum,
                        const int* __restrict__ fscan,
                        const int* __restrict__ dest, const int* __restrict__ posmap,
                        const int* __restrict__ rank_of, float* __restrict__ out){
  int t = blockIdx.x*256 + threadIdx.x; if (t >= kNT) return;
  int pat = tetinfo[t];
  int nt_ = c_ntri[pat];
  if (nt_ == 0) return;
  u64 tot = psum[kNT];
  int Nm1 = (int)(tot >> 44), Nm2 = (int)((tot >> 24) & 0xFFFFF);
  int Ne = fscan[CAP];
  long long faces_off = 3LL*Ne;
  long long uvidx_off = faces_off + 3LL*((long long)Nm1 + 2LL*Nm2) + UVS_FLOATS;
  u64 ps = psum[t];
  int m1v = (int)(ps >> 44), m2v = (int)((ps >> 24) & 0xFFFFF);
  int seq = (int)(ps & 0xFFFFFF);
  int er[6];
  int j = 0;
  #pragma unroll
  for (int e = 0; e < 6; e++){
    int i0 = c_edges[2*e], i1 = c_edges[2*e+1];
    if (((pat >> i0) & 1) != ((pat >> i1) & 1)){
      er[e] = rank_of[posmap[dest[seq + j]]];
      j++;
    } else er[e] = -1;
  }
  for (int k = 0; k < nt_; k++){
    long long row = (nt_ == 1) ? (long long)m1v : ((long long)Nm1 + 2LL*m2v + k);
    #pragma unroll
    for (int c = 0; c < 3; c++){
      int slot = c_tri[pat][3*k + c];
      out[faces_off + 3*row + c] = (float)er[slot];
    }
    out[uvidx_off + 3*row + 0] = (float)(4*t);
    out[uvidx_off + 3*row + 1] = (float)(4*t + k + 1);
    out[uvidx_off + 3*row + 2] = (float)(4*t + k + 2);
  }
}

__global__ void k_uvs(const u64* __restrict__ psum, const int* __restrict__ fscan,
                      float* __restrict__ out){
  long long r = (long long)blockIdx.x*256 + threadIdx.x;
  if (r >= UVS_ROWS) return;
  u64 tot = psum[kNT];
  int Nm1 = (int)(tot >> 44), Nm2 = (int)((tot >> 24) & 0xFFFFF);
  int Ne = fscan[CAP];
  long long off = 3LL*Ne + 3LL*((long long)Nm1 + 2LL*Nm2);
  int cell = (int)(r >> 2), k = (int)(r & 3);
  int iy = cell / kNUV, ix = cell - iy*kNUV;
  const float delta = (1.0f - 1.0f/895.0f) / 894.0f;   // linspace(0, 1-1/N, N) step, f32
  const float pad = 0.9f / 895.0f;
  float x = (float)ix * delta, y = (float)iy * delta;
  float u = x + ((k == 1 || k == 2) ? pad : 0.0f);
  float v = y + ((k >= 2) ? pad : 0.0f);
  out[off + 2*r]     = u;
  out[off + 2*r + 1] = v;
}

// ---------------- host ----------------
static inline int divup(int a, int b){ return (a + b - 1) / b; }

extern "C" void kernel_launch(void* const* d_in, const int* in_sizes, int n_in,
                              void* d_out, int out_size, void* d_ws, size_t ws_size,
                              hipStream_t stream){
  const float* pos = (const float*)d_in[0];
  const float* sdf = (const float*)d_in[1];
  const int*   tet = (const int*)d_in[2];
  float* out = (float*)d_out;

  char* ws = (char*)d_ws;
  size_t off = 0;
  auto alloc = [&](size_t bytes) -> char* {
    char* p = ws + off; off += (bytes + 255) & ~(size_t)255; return p;
  };
  int* tetinfo     = (int*)alloc((size_t)kNT*4);
  u64* pk          = (u64*)alloc((size_t)kNT*8);
  u64* psum        = (u64*)alloc((size_t)(kNT+1)*8);
  int* blockHist   = (int*)alloc((size_t)NBIN*NH*4);
  int* bhScan      = (int*)alloc((size_t)(NBIN*NH+1)*4);
  u64* ebin        = (u64*)alloc((size_t)CAP*8);
  u64* efin        = (u64*)alloc((size_t)CAP*8);
  int* dest        = (int*)alloc((size_t)CAP*4);
  int* posmap      = (int*)alloc((size_t)CAP*4);
  int* rank_of     = (int*)alloc((size_t)CAP*4);
  int* fscan       = (int*)alloc((size_t)(CAP+1)*4);
  u64* part64      = (u64*)alloc(4096*8);
  int* partI       = (int*)alloc(4096*4);
  // ebin is dead after k_fine: alias the flags outputs onto it
  int* firstI      = (int*)ebin;
  unsigned* meta   = (unsigned*)((char*)ebin + (size_t)CAP*4);
  if (off > ws_size){
    fprintf(stderr, "[dmtet] workspace too small: need %zu have %zu\n", off, ws_size);
    return;
  }

  k_classify_hist<<<NH, 256, 0, stream>>>(tet, sdf, tetinfo, pk, blockHist);
  run_scan<u64>(pk, psum, kNT, part64, stream);
  run_scan<int>(blockHist, bhScan, NBIN*NH, partI, stream);
  k_scatter<<<NH, 256, 0, stream>>>(tet, tetinfo, psum, bhScan, ebin, dest);
  k_fine<<<NBIN, 256, 0, stream>>>(bhScan, ebin, efin, posmap);
  k_flags<<<divup(CAP,FB), FB, 0, stream>>>(efin, bhScan + NBIN*NH, firstI, meta);
  run_scan<int>(firstI, fscan, CAP, partI, stream);
  k_emit<<<divup(CAP,256), 256, 0, stream>>>(efin, bhScan + NBIN*NH, fscan, meta,
                                             pos, sdf, out, rank_of);
  k_faces<<<divup(kNT,256), 256, 0, stream>>>(tetinfo, psum, fscan, dest, posmap, rank_of, out);
  k_uvs<<<divup((int)UVS_ROWS,256), 256, 0, stream>>>(psum, fscan, out);
}

// Round 7
// 225.002 us; speedup vs baseline: 3.0087x; 1.2501x over previous
//
#include <hip/hip_runtime.h>
#include <cstdio>
#include <cstdint>

typedef unsigned long long u64;

// ---------------- problem constants ----------------
static const int kNV = 200000;
static const int kNT = 800000;
static const int kNUV = 895;                       // ceil(sqrt((2*NT+1)//2))
#define UVS_ROWS   3204100LL                       // kNUV*kNUV*4
#define UVS_FLOATS 6408200LL                       // UVS_ROWS*2
#define CAP 3300000                                // max crossing-edge instances (<= 4*NT = 3.2M)

// counting-sort geometry
#define NH 392                                     // classify/hist/scatter blocks
#define TILE_T 2048                                // tets per block (NH*TILE_T >= kNT)
#define BINW 256                                   // a-values per coarse bin
#define NBIN 782                                   // ceil(200000/256)
#define SUBSH 15                                   // sub-bucket = (a, b>>SUBSH)
#define FINEB 2048                                 // BINW * (1<<(18-SUBSH)) fine cursors

__device__ const int c_tri[16][6] = {
    {-1,-1,-1,-1,-1,-1},{1,0,2,-1,-1,-1},{4,0,3,-1,-1,-1},{1,4,2,1,3,4},
    {3,1,5,-1,-1,-1},{2,3,0,2,5,3},{1,4,0,1,5,4},{4,2,5,-1,-1,-1},
    {4,5,2,-1,-1,-1},{4,1,0,4,5,1},{3,2,0,3,5,2},{1,3,5,-1,-1,-1},
    {4,1,2,4,3,1},{3,0,4,-1,-1,-1},{2,0,1,-1,-1,-1},{-1,-1,-1,-1,-1,-1}};
__device__ const int c_ntri[16]   = {0,1,1,2,1,2,2,1,1,2,2,1,2,1,1,0};
__device__ const int c_ncross[16] = {0,3,3,4,3,4,4,3,3,4,4,3,4,3,3,0};
__device__ const int c_edges[12] = {0,1,0,2,0,3,1,2,1,3,2,3};

// psum packing: m1 <<44 | m2 <<24 | ncross (m1,m2 totals < 2^20, ncross total < 2^24)
#define PK(m1,m2,nc) (((u64)(m1) << 44) | ((u64)(m2) << 24) | (u64)(nc))
// ebin packing: a <<40 | b <<22 | seq (a,b < 2^18, seq < 2^22); key36 = p>>22; group = key36>>SUBSH

// ---------------- generic exclusive scan (templated, 3 kernels) ----------------
#define SCAN_B 256
#define SCAN_I 8
#define SCAN_TILE (SCAN_B*SCAN_I)

template<typename T>
__global__ void k_scan_partial(const T* __restrict__ in, T* __restrict__ partials, int n){
  __shared__ T sm[SCAN_B];
  int b = blockIdx.x;
  long long base = (long long)b*SCAN_TILE;
  T sum = 0;
  for (int i = threadIdx.x; i < SCAN_TILE; i += SCAN_B){
    long long idx = base + i;
    if (idx < n) sum += in[idx];
  }
  sm[threadIdx.x] = sum; __syncthreads();
  for (int s = SCAN_B/2; s > 0; s >>= 1){
    if ((int)threadIdx.x < s) sm[threadIdx.x] += sm[threadIdx.x + s];
    __syncthreads();
  }
  if (threadIdx.x == 0) partials[b] = sm[0];
}

template<typename T>
__global__ void k_scan_blocksums(T* __restrict__ partials, int nb, T* __restrict__ total_out){
  __shared__ T sm[SCAN_B];
  T carry = 0;
  for (int base = 0; base < nb; base += SCAN_B){
    int i = base + (int)threadIdx.x;
    T v = (i < nb) ? partials[i] : (T)0;
    sm[threadIdx.x] = v; __syncthreads();
    for (int off = 1; off < SCAN_B; off <<= 1){
      T t = ((int)threadIdx.x >= off) ? sm[threadIdx.x - off] : (T)0;
      __syncthreads();
      sm[threadIdx.x] += t;
      __syncthreads();
    }
    if (i < nb) partials[i] = carry + sm[threadIdx.x] - v;  // exclusive
    T tilesum = sm[SCAN_B-1];
    __syncthreads();
    carry += tilesum;
  }
  if (threadIdx.x == 0 && total_out) *total_out = carry;
}

template<typename T>
__global__ void k_scan_apply(const T* __restrict__ in, T* __restrict__ out,
                             const T* __restrict__ partials, int n){
  __shared__ T sm[SCAN_B];
  int b = blockIdx.x;
  long long base = (long long)b*SCAN_TILE + (long long)threadIdx.x*SCAN_I;
  T v[SCAN_I]; T s = 0;
  #pragma unroll
  for (int k = 0; k < SCAN_I; k++){ long long idx = base + k; v[k] = (idx < n) ? in[idx] : (T)0; s += v[k]; }
  sm[threadIdx.x] = s; __syncthreads();
  for (int off = 1; off < 256; off <<= 1){
    T t = ((int)threadIdx.x >= off) ? sm[threadIdx.x - off] : (T)0;
    __syncthreads();
    sm[threadIdx.x] += t;
    __syncthreads();
  }
  T excl = sm[threadIdx.x] - s + partials[b];
  #pragma unroll
  for (int k = 0; k < SCAN_I; k++){ long long idx = base + k; if (idx < n) out[idx] = excl; excl += v[k]; }
}

template<typename T>
static void run_scan(const T* in, T* out, int n, T* partials, hipStream_t s){
  int nb = (n + SCAN_TILE - 1) / SCAN_TILE;
  k_scan_partial<T><<<nb, SCAN_B, 0, s>>>(in, partials, n);
  k_scan_blocksums<T><<<1, SCAN_B, 0, s>>>(partials, nb, out + n);  // total -> out[n]
  k_scan_apply<T><<<nb, SCAN_B, 0, s>>>(in, out, partials, n);
}

// ---------------- pipeline kernels ----------------

// fused: per-tet occupancy pattern + (m1,m2,ncross) pack + coarse-bin histogram
__global__ void k_classify_hist(const int* __restrict__ tet, const float* __restrict__ sdf,
                                int* __restrict__ tetinfo, u64* __restrict__ pk,
                                int* __restrict__ blockHist){
  __shared__ int h[NBIN];
  int blk = blockIdx.x;
  for (int j = threadIdx.x; j < NBIN; j += 256) h[j] = 0;
  __syncthreads();
  int t0 = blk*TILE_T;
  for (int k = 0; k < TILE_T/256; k++){
    int t = t0 + k*256 + threadIdx.x;
    if (t < kNT){
      int4 v4 = ((const int4*)tet)[t];
      int pat = ((sdf[v4.x] > 0.0f) ? 1 : 0) | ((sdf[v4.y] > 0.0f) ? 2 : 0)
              | ((sdf[v4.z] > 0.0f) ? 4 : 0) | ((sdf[v4.w] > 0.0f) ? 8 : 0);
      tetinfo[t] = pat;
      int nt_ = c_ntri[pat];
      pk[t] = PK(nt_ == 1, nt_ == 2, c_ncross[pat]);
      if (pat != 0 && pat != 15){
        int vv[4] = {v4.x, v4.y, v4.z, v4.w};
        #pragma unroll
        for (int e = 0; e < 6; e++){
          int i0 = c_edges[2*e], i1 = c_edges[2*e+1];
          if (((pat >> i0) & 1) != ((pat >> i1) & 1)){
            int a = vv[i0], b = vv[i1]; if (a > b){ int tm = a; a = b; b = tm; }
            atomicAdd(&h[a >> 8], 1);
          }
        }
      }
    }
  }
  __syncthreads();
  for (int j = threadIdx.x; j < NBIN; j += 256) blockHist[j*NH + blk] = h[j];  // bin-major
}

// scatter instances to bin-grouped buffer via LDS cursors (payload = seq)
__global__ void k_scatter(const int* __restrict__ tet, const int* __restrict__ tetinfo,
                          const u64* __restrict__ psum, const int* __restrict__ bhScan,
                          u64* __restrict__ ebin){
  __shared__ int c[NBIN];
  int blk = blockIdx.x;
  for (int j = threadIdx.x; j < NBIN; j += 256) c[j] = bhScan[j*NH + blk];
  __syncthreads();
  int t0 = blk*TILE_T;
  for (int k = 0; k < TILE_T/256; k++){
    int t = t0 + k*256 + threadIdx.x;
    if (t < kNT){
      int pat = tetinfo[t];
      if (pat != 0 && pat != 15){
        int4 v4 = ((const int4*)tet)[t];
        int vv[4] = {v4.x, v4.y, v4.z, v4.w};
        int seq = (int)(psum[t] & 0xFFFFFF);
        #pragma unroll
        for (int e = 0; e < 6; e++){
          int i0 = c_edges[2*e], i1 = c_edges[2*e+1];
          if (((pat >> i0) & 1) != ((pat >> i1) & 1)){
            int a = vv[i0], b = vv[i1]; if (a > b){ int tm = a; a = b; b = tm; }
            int pos = atomicAdd(&c[a >> 8], 1);
            ebin[pos] = ((u64)(unsigned)a << 40) | ((u64)(unsigned)b << 22) | (unsigned)seq;
            seq++;
          }
        }
      }
    }
  }
}

// per coarse bin: regroup by fine key (a&255)<<3 | b>>15.
// efin ends up globally sorted by (a, b>>15) -> groups for k_flags are tiny (k ~ 1.5).
__global__ void k_fine(const int* __restrict__ bhScan, const u64* __restrict__ ebin,
                       u64* __restrict__ efin){
  __shared__ int h[FINEB];
  __shared__ int ss[256];
  int bin = blockIdx.x;
  int binStart = bhScan[bin*NH];
  int binEnd   = bhScan[(bin+1)*NH];     // scan stores total at [n] for the last bin
  int a0 = bin << 8;
  for (int j = threadIdx.x; j < FINEB; j += 256) h[j] = 0;
  __syncthreads();
  for (int i = binStart + threadIdx.x; i < binEnd; i += 256){
    u64 p = ebin[i];
    int a = (int)(p >> 40);
    int bh = (int)((p >> 22) & 0x3FFFF) >> SUBSH;
    atomicAdd(&h[((a - a0) << 3) | bh], 1);
  }
  __syncthreads();
  // exclusive scan of h[2048] with 256 threads (8 elements each)
  int tid = threadIdx.x;
  int base8 = tid*8;
  int loc[8]; int s = 0;
  #pragma unroll
  for (int q = 0; q < 8; q++){ loc[q] = h[base8+q]; s += loc[q]; }
  ss[tid] = s; __syncthreads();
  for (int off = 1; off < 256; off <<= 1){
    int v = (tid >= off) ? ss[tid - off] : 0;
    __syncthreads();
    ss[tid] += v;
    __syncthreads();
  }
  int excl = ss[tid] - s;
  #pragma unroll
  for (int q = 0; q < 8; q++){ h[base8+q] = excl; excl += loc[q]; }
  __syncthreads();
  // regroup: h serves as per-fine-key cursors (exclusive offsets)
  for (int i = binStart + tid; i < binEnd; i += 256){
    u64 p = ebin[i];
    int a = (int)(p >> 40);
    int bh = (int)((p >> 22) & 0x3FFFF) >> SUBSH;
    int pos = binStart + atomicAdd(&h[((a - a0) << 3) | bh], 1);
    efin[pos] = p;
  }
}

// item-parallel first/rank/off over (a,b>>15)-sorted efin, LDS window with halos.
#define FB 256
#define FH 32
#define FW (FB + 2*FH)   // 320
__global__ void k_flags(const u64* __restrict__ efin, const int* __restrict__ totp,
                        int* __restrict__ firstI, unsigned* __restrict__ meta){
  __shared__ u64 ld[FW];
  __shared__ unsigned char fl[FW];
  int total = *totp;
  int tid = threadIdx.x;
  long long base = (long long)blockIdx.x * FB;
  long long gi = base + tid;
  if (base >= total){                       // pure tail block: zero-fill, no window
    if (gi < CAP){ firstI[gi] = 0; meta[gi] = 0; }
    return;
  }
  for (int x = tid; x < FW; x += FB){
    long long g = base - FH + x;
    ld[x] = (g >= 0 && g < total) ? (efin[g] >> 22) : ~0ULL;   // key36 = a<<18 | b
  }
  __syncthreads();
  // phase 1: first-occurrence flags for window + halos (left scan within group)
  for (int x = tid; x < FW; x += FB){
    u64 key = ld[x];
    u64 grp = key >> SUBSH;
    unsigned char f = 1;
    for (int y = x-1; y >= 0; y--){
      u64 ky = ld[y];
      if ((ky >> SUBSH) != grp) break;
      if (ky == key){ f = 0; break; }
    }
    fl[x] = f;
  }
  __syncthreads();
  // phase 2: per item: group range, rank = #distinct smaller keys in group
  if (gi < total){
    int x = FH + tid;
    u64 key = ld[x];
    u64 grp = key >> SUBSH;
    int sx = x; while (sx > 0 && (ld[sx-1] >> SUBSH) == grp) sx--;
    int ex = x+1; while (ex < FW && (ld[ex] >> SUBSH) == grp) ex++;
    int first, rank, off;
    if (sx > 0 && ex < FW){
      first = fl[x];
      int rk = 0;
      for (int y = sx; y < ex; y++) if (fl[y] && ld[y] < key) rk++;
      rank = rk; off = x - sx;
    } else {
      // slow path: group spans past the LDS window (group > 32 items; statistically never)
      u64 keyg = efin[gi] >> 22;
      u64 grpg = keyg >> SUBSH;
      long long s = gi; while (s > 0 && ((efin[s-1] >> 22) >> SUBSH) == grpg) s--;
      long long e = gi + 1; while (e < total && ((efin[e] >> 22) >> SUBSH) == grpg) e++;
      int f = 1;
      for (long long j = s; j < gi; j++) if ((efin[j] >> 22) == keyg){ f = 0; break; }
      int rk = 0;
      for (long long j = s; j < e; j++){
        u64 kj = efin[j] >> 22;
        if (kj < keyg){
          bool fj = true;
          for (long long l = s; l < j; l++) if ((efin[l] >> 22) == kj){ fj = false; break; }
          if (fj) rk++;
        }
      }
      first = f; rank = rk; off = (int)(gi - s);
    }
    firstI[gi] = first;
    meta[gi] = (unsigned)rank | ((unsigned)off << 12) | ((unsigned)first << 24);
  } else if (gi < CAP){
    firstI[gi] = 0;      // straddling block's tail: zero-fill for exact CAP-length scan
    meta[gi] = 0;
  }
}

// item-parallel: r = fscan[group_start] + rank; emit verts (firsts) + rankBySeq scatter
__global__ void k_emit(const u64* __restrict__ efin, const int* __restrict__ totp,
                       const int* __restrict__ fscan, const unsigned* __restrict__ meta,
                       const float* __restrict__ pos, const float* __restrict__ sdf,
                       float* __restrict__ out, int* __restrict__ rankBySeq){
  int total = *totp;
  int i = blockIdx.x*256 + threadIdx.x;
  if (i >= total) return;
  u64 p = efin[i];
  unsigned m = meta[i];
  int rank = m & 0xFFF, off = (m >> 12) & 0xFFF, first = (m >> 24) & 1;
  int r = fscan[i - off] + rank;
  rankBySeq[(int)(p & 0x3FFFFF)] = r;      // inverted join: one random write per instance
  if (first){
    int a = (int)(p >> 40);
    int b = (int)((p >> 22) & 0x3FFFF);
    float sa = sdf[a], sb = sdf[b];
    float denom = sa - sb;               // s = [sa,-sb]; never 0 for a crossing edge
    float w0 = (-sb) / denom;
    float w1 = sa / denom;
    out[3LL*r + 0] = pos[3*a+0]*w0 + pos[3*b+0]*w1;
    out[3LL*r + 1] = pos[3*a+1]*w0 + pos[3*b+1]*w1;
    out[3LL*r + 2] = pos[3*a+2]*w0 + pos[3*b+2]*w1;
  }
}

// faces + uv_idx: er[j] = rankBySeq[seq + j] — fully sequential reads
__global__ void k_faces(const int* __restrict__ tetinfo, const u64* __restrict__ psum,
                        const int* __restrict__ fscan, const int* __restrict__ rankBySeq,
                        float* __restrict__ out){
  int t = blockIdx.x*256 + threadIdx.x; if (t >= kNT) return;
  int pat = tetinfo[t];
  int nt_ = c_ntri[pat];
  if (nt_ == 0) return;
  u64 tot = psum[kNT];
  int Nm1 = (int)(tot >> 44), Nm2 = (int)((tot >> 24) & 0xFFFFF);
  int Ne = fscan[CAP];
  long long faces_off = 3LL*Ne;
  long long uvidx_off = faces_off + 3LL*((long long)Nm1 + 2LL*Nm2) + UVS_FLOATS;
  u64 ps = psum[t];
  int m1v = (int)(ps >> 44), m2v = (int)((ps >> 24) & 0xFFFFF);
  int seq = (int)(ps & 0xFFFFFF);
  int er[6];
  int j = 0;
  #pragma unroll
  for (int e = 0; e < 6; e++){
    int i0 = c_edges[2*e], i1 = c_edges[2*e+1];
    if (((pat >> i0) & 1) != ((pat >> i1) & 1)){
      er[e] = rankBySeq[seq + j];
      j++;
    } else er[e] = -1;
  }
  for (int k = 0; k < nt_; k++){
    long long row = (nt_ == 1) ? (long long)m1v : ((long long)Nm1 + 2LL*m2v + k);
    #pragma unroll
    for (int c = 0; c < 3; c++){
      int slot = c_tri[pat][3*k + c];
      out[faces_off + 3*row + c] = (float)er[slot];
    }
    out[uvidx_off + 3*row + 0] = (float)(4*t);
    out[uvidx_off + 3*row + 1] = (float)(4*t + k + 1);
    out[uvidx_off + 3*row + 2] = (float)(4*t + k + 2);
  }
}

__global__ void k_uvs(const u64* __restrict__ psum, const int* __restrict__ fscan,
                      float* __restrict__ out){
  long long r = (long long)blockIdx.x*256 + threadIdx.x;
  if (r >= UVS_ROWS) return;
  u64 tot = psum[kNT];
  int Nm1 = (int)(tot >> 44), Nm2 = (int)((tot >> 24) & 0xFFFFF);
  int Ne = fscan[CAP];
  long long off = 3LL*Ne + 3LL*((long long)Nm1 + 2LL*Nm2);
  int cell = (int)(r >> 2), k = (int)(r & 3);
  int iy = cell / kNUV, ix = cell - iy*kNUV;
  const float delta = (1.0f - 1.0f/895.0f) / 894.0f;   // linspace(0, 1-1/N, N) step, f32
  const float pad = 0.9f / 895.0f;
  float x = (float)ix * delta, y = (float)iy * delta;
  float u = x + ((k == 1 || k == 2) ? pad : 0.0f);
  float v = y + ((k >= 2) ? pad : 0.0f);
  out[off + 2*r]     = u;
  out[off + 2*r + 1] = v;
}

// ---------------- host ----------------
static inline int divup(int a, int b){ return (a + b - 1) / b; }

extern "C" void kernel_launch(void* const* d_in, const int* in_sizes, int n_in,
                              void* d_out, int out_size, void* d_ws, size_t ws_size,
                              hipStream_t stream){
  const float* pos = (const float*)d_in[0];
  const float* sdf = (const float*)d_in[1];
  const int*   tet = (const int*)d_in[2];
  float* out = (float*)d_out;

  char* ws = (char*)d_ws;
  size_t off = 0;
  auto alloc = [&](size_t bytes) -> char* {
    char* p = ws + off; off += (bytes + 255) & ~(size_t)255; return p;
  };
  int* tetinfo     = (int*)alloc((size_t)kNT*4);
  u64* pk          = (u64*)alloc((size_t)kNT*8);
  u64* psum        = (u64*)alloc((size_t)(kNT+1)*8);
  int* blockHist   = (int*)alloc((size_t)NBIN*NH*4);
  int* bhScan      = (int*)alloc((size_t)(NBIN*NH+1)*4);
  u64* ebin        = (u64*)alloc((size_t)CAP*8);
  u64* efin        = (u64*)alloc((size_t)CAP*8);
  int* rankBySeq   = (int*)alloc((size_t)CAP*4);
  int* fscan       = (int*)alloc((size_t)(CAP+1)*4);
  u64* part64      = (u64*)alloc(4096*8);
  int* partI       = (int*)alloc(4096*4);
  // ebin is dead after k_fine: alias the flags outputs onto it
  int* firstI      = (int*)ebin;
  unsigned* meta   = (unsigned*)((char*)ebin + (size_t)CAP*4);
  if (off > ws_size){
    fprintf(stderr, "[dmtet] workspace too small: need %zu have %zu\n", off, ws_size);
    return;
  }

  k_classify_hist<<<NH, 256, 0, stream>>>(tet, sdf, tetinfo, pk, blockHist);
  run_scan<u64>(pk, psum, kNT, part64, stream);
  run_scan<int>(blockHist, bhScan, NBIN*NH, partI, stream);
  k_scatter<<<NH, 256, 0, stream>>>(tet, tetinfo, psum, bhScan, ebin);
  k_fine<<<NBIN, 256, 0, stream>>>(bhScan, ebin, efin);
  k_flags<<<divup(CAP,FB), FB, 0, stream>>>(efin, bhScan + NBIN*NH, firstI, meta);
  run_scan<int>(firstI, fscan, CAP, partI, stream);
  k_emit<<<divup(CAP,256), 256, 0, stream>>>(efin, bhScan + NBIN*NH, fscan, meta,
                                             pos, sdf, out, rankBySeq);
  k_faces<<<divup(kNT,256), 256, 0, stream>>>(tetinfo, psum, fscan, rankBySeq, out);
  k_uvs<<<divup((int)UVS_ROWS,256), 256, 0, stream>>>(psum, fscan, out);
}